// Round 9
// baseline (53697.919 us; speedup 1.0000x reference)
//
#include <hip/hip_runtime.h>
#include <hip/hip_bf16.h>
#include <hip/hip_fp16.h>

typedef _Float16 f16;
typedef _Float16 f16x2 __attribute__((ext_vector_type(2)));
typedef _Float16 f16x4 __attribute__((ext_vector_type(4)));
typedef _Float16 f16x8 __attribute__((ext_vector_type(8)));
typedef float f32x4 __attribute__((ext_vector_type(4)));
typedef unsigned long long u64;

#define S_LEN 16384
#define NRULES 2048
#define CAP 2000000    // safecell spin cap: protocol failure -> bounded abort
#define FAST_TRIES 64  // bounded fastcell probe before sticky fallback

// ---- ws layout (bytes) ----
#define H1SEQ_OFF 0u                    // 16 MB f16 [S][512]
#define ACTW_OFF  (16u*1024*1024)       // 2 MB f16 action_W
#define WIH0_OFF  (18u*1024*1024)       // 3 MB f16 W_ih0
#define HB0F_OFF  (21u*1024*1024)           // 2*256 u64 fastcells h0
#define HB0S_OFF  (21u*1024*1024 + 4096)    // 2*256 u64 safecells h0
#define HB1F_OFF  (21u*1024*1024 + 8192)    // 2*256 u64 fastcells h1
#define HB1S_OFF  (21u*1024*1024 + 12288)   // 2*256 u64 safecells h1
// d_out overlay: [0,48M) xi0 f16 [S,1536]; [48M,80M) X f16 [S,1024]

#if __has_builtin(__builtin_amdgcn_rcpf)
#define RCPF(x) __builtin_amdgcn_rcpf(x)
#else
#define RCPF(x) (1.0f/(x))
#endif

union F2U { f16x2 f; unsigned u; };

__device__ __forceinline__ float sigf(float x){ return RCPF(1.0f + __expf(-x)); }
__device__ __forceinline__ float tanh_fast(float x){
  float ax = fabsf(x);
  float e = __expf(-2.0f*ax);
  float t = (1.0f - e) * RCPF(1.0f + e);
  return x >= 0.0f ? t : -t;
}
__device__ __forceinline__ float dot2(f16x2 a, f16x2 b, float c){
#if __has_builtin(__builtin_amdgcn_fdot2)
  return __builtin_amdgcn_fdot2(a, b, c, false);
#else
  return c + (float)a.x*(float)b.x + (float)a.y*(float)b.y;
#endif
}
// proven authoritative primitives (coherence point):
__device__ __forceinline__ u64 aload64(const u64* p){
  return __hip_atomic_load(p, __ATOMIC_RELAXED, __HIP_MEMORY_SCOPE_AGENT);
}
__device__ __forceinline__ void apub64(u64* p, u64 v){
  (void)__hip_atomic_exchange(p, v, __ATOMIC_RELAXED, __HIP_MEMORY_SCOPE_AGENT);
}
// fast-path primitives (same-XCD L2), proven in rounds 7/8:
__device__ __forceinline__ u64 load_sc0_u64(const u64* p){
  u64 v;
  asm volatile("global_load_dwordx2 %0, %1, off sc0\n\ts_waitcnt vmcnt(0)"
               : "=v"(v) : "v"(p) : "memory");
  return v;
}
__device__ __forceinline__ void store_u64(u64* p, u64 v){
  asm volatile("global_store_dwordx2 %0, %1, off"
               :: "v"(p), "v"(v) : "memory");
}
// LDS-only barrier (drains lgkm, NOT vmcnt) — publishes stay in flight.
#define BAR_LGKM() asm volatile("s_waitcnt lgkmcnt(0)\n\ts_barrier" ::: "memory")

// ---------------- gather x = [emb[shifted], emb[parent]] as f16 ----------------
__global__ __launch_bounds__(256) void gather_x(
    const float* __restrict__ emb, const int* __restrict__ act,
    const int* __restrict__ par, f16* __restrict__ X)
{
  const int t = blockIdx.x, lid = threadIdx.x;
  const int ia = (t == 0) ? 0 : (act[t-1] + 1);
  const int ip = par[t] + 1;
  const int half = lid >> 7;
  const int k = (lid & 127) << 2;
  const float* src = emb + (size_t)(half ? ip : ia) * 512 + k;
  float4 v = *(const float4*)src;
  f16x4 o; o.x=(f16)v.x; o.y=(f16)v.y; o.z=(f16)v.z; o.w=(f16)v.w;
  *(f16x4*)&X[(size_t)t*1024 + (half<<9) + k] = o;
}

// ---------------- fp32 -> f16 convert ----------------
__global__ __launch_bounds__(256) void cvt_k(const float* __restrict__ in,
                                             f16* __restrict__ out, int n)
{
  const int i = (blockIdx.x*256 + threadIdx.x) << 2;
  if (i >= n) return;
  float4 v = *(const float4*)&in[i];
  f16x4 o; o.x=(f16)v.x; o.y=(f16)v.y; o.z=(f16)v.z; o.w=(f16)v.w;
  *(f16x4*)&out[i] = o;
}

// ---- per-call init: invalidate every tagged cell (replay-stale tag safety) ----
__global__ __launch_bounds__(256) void init_ctrl(char* ws)
{
  const int lid = threadIdx.x;
  const u64 inval = (u64)0xF0000000u << 32;   // tag never matched
  u64* F0 = (u64*)(ws + HB0F_OFF);
  u64* S0 = (u64*)(ws + HB0S_OFF);
  u64* F1 = (u64*)(ws + HB1F_OFF);
  u64* S1 = (u64*)(ws + HB1S_OFF);
  F0[lid]=inval; F0[256+lid]=inval;
  S0[lid]=inval; S0[256+lid]=inval;
  F1[lid]=inval; F1[256+lid]=inval;
  S1[lid]=inval; S1[256+lid]=inval;
}

// ---------------- f16 MFMA GEMM: C[M,N] = A[M,K] @ B[N,K]^T + bias ----------------
template<typename OutT>
__global__ __launch_bounds__(256) void gemm_f16(
    const f16* __restrict__ A, const f16* __restrict__ B,
    const float* __restrict__ bias, OutT* __restrict__ C,
    int M, int N, int K)
{
  __shared__ __align__(16) f16 At[4][128][8];
  __shared__ __align__(16) f16 Bt[4][128][8];
  const int lid = threadIdx.x;
  const int mtiles = M >> 7;
  const int bm = blockIdx.x % mtiles;
  const int bn = blockIdx.x / mtiles;
  const int m0 = bm << 7, n0 = bn << 7;
  const int lane = lid & 63, w = lid >> 6;
  const int wm = (w >> 1) << 6, wn = (w & 1) << 6;
  f32x4 acc[4][4] = {};
  const int nk = K >> 5;
  const int row1 = lid >> 2, j1 = lid & 3;
  for (int kt = 0; kt < nk; ++kt){
    const int kb = kt << 5;
    *(f16x8*)&At[j1][row1][0]    = *(const f16x8*)&A[(size_t)(m0+row1)*K    + kb + j1*8];
    *(f16x8*)&At[j1][row1+64][0] = *(const f16x8*)&A[(size_t)(m0+row1+64)*K + kb + j1*8];
    *(f16x8*)&Bt[j1][row1][0]    = *(const f16x8*)&B[(size_t)(n0+row1)*K    + kb + j1*8];
    *(f16x8*)&Bt[j1][row1+64][0] = *(const f16x8*)&B[(size_t)(n0+row1+64)*K + kb + j1*8];
    __syncthreads();
    const int kc = lane >> 4, rr = lane & 15;
    f16x8 aF[4], bF[4];
    #pragma unroll
    for (int m=0;m<4;m++) aF[m] = *(const f16x8*)&At[kc][wm + m*16 + rr][0];
    #pragma unroll
    for (int n=0;n<4;n++) bF[n] = *(const f16x8*)&Bt[kc][wn + n*16 + rr][0];
    #pragma unroll
    for (int m=0;m<4;m++)
      #pragma unroll
      for (int n=0;n<4;n++)
        acc[m][n] = __builtin_amdgcn_mfma_f32_16x16x32_f16(aF[m], bF[n], acc[m][n], 0,0,0);
    __syncthreads();
  }
  const int rr = lane & 15, rg = lane >> 4;
  #pragma unroll
  for (int n=0;n<4;n++){
    const int gcol = n0 + wn + n*16 + rr;
    const float bv = bias[gcol];
    #pragma unroll
    for (int m=0;m<4;m++){
      #pragma unroll
      for (int r=0;r<4;r++){
        const int grow = m0 + wm + m*16 + rg*4 + r;
        C[(size_t)grow*N + gcol] = (OutT)(acc[m][n][r] + bv);
      }
    }
  }
}

// ---- merged fused 2-layer scan: 16 blocks x 768 threads, 1 barrier/step ----
// Participants: bid%8==0 (grp = bid>>3 in [0,16)) — same XCD if dispatch
// round-robins (validated r7); per-thread sticky safecell fallback otherwise.
// Threads 0-255:  layer0, 32 rows/block, 8 thr/row (ksub=lid&7).
// Threads 256-767: layer1, 32 rows/block, 16 thr/row — ksub16<8 computes
//   W_ih·h0 gates, ksub16>=8 computes W_hh·h1 gates; xor-8 shuffle combines.
// Step q: L0 computes h0[q] (q<S) from hb[q&1]; L1 computes h1[q-1] (q>=1).
// Order per step: compute -> publish own tagged cells (tag q+1, parity
// (q+1)&1) -> poll peers' tag q+1 cells -> stage hb[(q+1)&1] -> BAR_LGKM.
// Polling after publishing absorbs peer skew + publish visibility.
__global__ __launch_bounds__(768, 1) void scan_m(
    const float* __restrict__ Whh0, const float* __restrict__ bhh0,
    const float* __restrict__ Wih1, const float* __restrict__ bih1,
    const float* __restrict__ Whh1, const float* __restrict__ bhh1,
    const float* __restrict__ init, const f16* __restrict__ xi0,
    char* ws)
{
  const int lid = threadIdx.x, bid = blockIdx.x;
  if (bid & 7) return;
  const int grp = bid >> 3;            // 0..15
  f16x2* h1seq = (f16x2*)(ws + H1SEQ_OFF);
  u64* F0 = (u64*)(ws + HB0F_OFF);
  u64* S0 = (u64*)(ws + HB0S_OFF);
  u64* F1 = (u64*)(ws + HB1F_OFF);
  u64* S1 = (u64*)(ws + HB1S_OFF);
  __shared__ f16x2 hb[2][512];         // [parity][h0:0-255 | h1:256-511]
  bool fast_ok = true;

  if (lid < 256){
    // ================= layer 0 =================
    const int ksub = lid & 7, r = lid >> 3, row = (grp << 5) + r;
    const bool owner = (ksub == 0);
    f16x2 wr[32], wz[32], wn[32];
    #pragma unroll
    for (int i=0;i<32;i++){
      const int k0 = (ksub + (i<<3)) << 1;
      float2 a = *(const float2*)&Whh0[(size_t)row*512         + k0];
      float2 b = *(const float2*)&Whh0[(size_t)(512+row)*512   + k0];
      float2 c = *(const float2*)&Whh0[(size_t)(1024+row)*512  + k0];
      wr[i].x=(f16)a.x; wr[i].y=(f16)a.y;
      wz[i].x=(f16)b.x; wz[i].y=(f16)b.y;
      wn[i].x=(f16)c.x; wn[i].y=(f16)c.y;
    }
    float bhr=0.f,bhz=0.f,bhn=0.f, xr=0.f,xz=0.f,xn=0.f, pxr=0.f,pxz=0.f,pxn=0.f;
    if (owner){
      bhr=bhh0[row]; bhz=bhh0[512+row]; bhn=bhh0[1024+row];
      xr=(float)xi0[row]; xz=(float)xi0[512+row]; xn=(float)xi0[1024+row];
    }
    { F2U s; s.f.x=(f16)init[2*lid]; s.f.y=(f16)init[2*lid+1]; hb[0][lid]=s.f; }
    BAR_LGKM();

    for (int q=0; q<=S_LEN; ++q){
      const int p = (q+1)&1;
      if (q < S_LEN){
        if (owner && q+1 < S_LEN){       // prefetch next xi (overlaps step)
          const f16* xp = xi0 + (size_t)(q+1)*1536;
          pxr=(float)xp[row]; pxz=(float)xp[512+row]; pxn=(float)xp[1024+row];
        }
        const f16x2* cur = hb[q&1];
        float ar=0.f, az=0.f, an=0.f;
        #pragma unroll
        for (int i=0;i<32;i++){
          f16x2 hv = cur[ksub + (i<<3)];
          ar = dot2(wr[i],hv,ar); az = dot2(wz[i],hv,az); an = dot2(wn[i],hv,an);
        }
        ar += __shfl_xor(ar,1); ar += __shfl_xor(ar,2); ar += __shfl_xor(ar,4);
        az += __shfl_xor(az,1); az += __shfl_xor(az,2); az += __shfl_xor(az,4);
        an += __shfl_xor(an,1); an += __shfl_xor(an,2); an += __shfl_xor(an,4);
        float hnew = 0.f;
        if (owner){
          float r_ = sigf(xr + ar + bhr);
          float z_ = sigf(xz + az + bhz);
          float nl = tanh_fast(xn + r_*(an + bhn));
          hnew = (1.0f - z_)*nl + z_*(float)cur[row>>1][row&1];
          xr=pxr; xz=pxz; xn=pxn;
        }
        float hp = __shfl(hnew, ((lid&63)+8)&63);
        if ((lid & 15) == 0){            // even-row owner publishes pair cell
          F2U pr; pr.f.x=(f16)hnew; pr.f.y=(f16)hp;
          const int j = (grp<<4) + (lid>>4);
          const u64 tg = ((u64)(unsigned)(q+1)<<32) | (u64)pr.u;
          store_u64(&F0[p*256 + j], tg);
          apub64(&S0[p*256 + j], tg);
        }
        // poll h0 cell lid for next step (tag q+1, parity p)
        {
          const u64* pf = F0 + p*256 + lid;
          const u64* ps = S0 + p*256 + lid;
          u64 cell=0; bool got=false;
          if (fast_ok){
            for (int k=0;k<FAST_TRIES;k++){
              u64 v = load_sc0_u64(pf);
              if ((unsigned)(v>>32) == (unsigned)(q+1)){ cell=v; got=true; break; }
            }
            if (!got) fast_ok = false;
          }
          if (!got){
            int it=0;
            for(;;){ u64 v = aload64(ps);
                     if ((unsigned)(v>>32) == (unsigned)(q+1)){ cell=v; break; }
                     if (++it > CAP){ cell=v; break; } }
          }
          F2U cu; cu.u = (unsigned)cell; hb[p][lid] = cu.f;
        }
      }
      BAR_LGKM();
    }
  } else {
    // ================= layer 1 (split W_ih | W_hh) =================
    const int local = lid - 256;
    const int ksub16 = local & 15, ksubh = ksub16 & 7;
    const int r = local >> 4, row = (grp << 5) + r;
    const bool grpA = (ksub16 < 8);
    const bool owner = (ksub16 == 0);
    const float* Wsel = grpA ? Wih1 : Whh1;
    const int base = grpA ? 0 : 256;
    f16x2 wa[32], wb[32], wc[32];
    #pragma unroll
    for (int i=0;i<32;i++){
      const int k0 = (ksubh + (i<<3)) << 1;
      float2 a = *(const float2*)&Wsel[(size_t)row*512         + k0];
      float2 b = *(const float2*)&Wsel[(size_t)(512+row)*512   + k0];
      float2 c = *(const float2*)&Wsel[(size_t)(1024+row)*512  + k0];
      wa[i].x=(f16)a.x; wa[i].y=(f16)a.y;
      wb[i].x=(f16)b.x; wb[i].y=(f16)b.y;
      wc[i].x=(f16)c.x; wc[i].y=(f16)c.y;
    }
    float bir=0.f,biz=0.f,bin=0.f, bhr=0.f,bhz=0.f,bhn=0.f;
    if (owner){
      bir=bih1[row]; biz=bih1[512+row]; bin=bih1[1024+row];
      bhr=bhh1[row]; bhz=bhh1[512+row]; bhn=bhh1[1024+row];
    }
    if (local < 256){
      F2U s; s.f.x=(f16)init[512+2*local]; s.f.y=(f16)init[512+2*local+1];
      hb[0][256+local] = s.f;
    }
    BAR_LGKM();

    for (int q=0; q<=S_LEN; ++q){
      const int p = (q+1)&1;
      if (q >= 1){
        const f16x2* cur = hb[q&1];
        float sa=0.f, sb=0.f, sc=0.f;
        #pragma unroll
        for (int i=0;i<32;i++){
          f16x2 hv = cur[base + ksubh + (i<<3)];
          sa = dot2(wa[i],hv,sa); sb = dot2(wb[i],hv,sb); sc = dot2(wc[i],hv,sc);
        }
        sa += __shfl_xor(sa,1); sa += __shfl_xor(sa,2); sa += __shfl_xor(sa,4);
        sb += __shfl_xor(sb,1); sb += __shfl_xor(sb,2); sb += __shfl_xor(sb,4);
        sc += __shfl_xor(sc,1); sc += __shfl_xor(sc,2); sc += __shfl_xor(sc,4);
        float oa = __shfl_xor(sa,8), ob = __shfl_xor(sb,8), oc = __shfl_xor(sc,8);
        float hnew = 0.f;
        if (owner){                      // own = W_ih sums; xor8 = W_hh sums
          float r_ = sigf(sa + bir + oa + bhr);
          float z_ = sigf(sb + biz + ob + bhz);
          float nl = tanh_fast(sc + bin + r_*(oc + bhn));
          hnew = (1.0f - z_)*nl + z_*(float)cur[256 + (row>>1)][row&1];
        }
        float hp = __shfl(hnew, ((lid&63)+16)&63);
        if ((local & 31) == 0){          // even-row owner publishes pair cell
          F2U pr; pr.f.x=(f16)hnew; pr.f.y=(f16)hp;
          const int j = (grp<<4) + (local>>5);
          h1seq[(size_t)(q-1)*256 + j] = pr.f;    // plain; read post-kernel
          if (q < S_LEN){
            const u64 tg = ((u64)(unsigned)(q+1)<<32) | (u64)pr.u;
            store_u64(&F1[p*256 + j], tg);
            apub64(&S1[p*256 + j], tg);
          }
        }
      }
      // stage h1 for next step
      if (q == 0){
        if (local < 256) hb[1][256+local] = hb[0][256+local];   // h1[-1] seed
      } else if (q < S_LEN && local < 256){
        const u64* pf = F1 + p*256 + local;
        const u64* ps = S1 + p*256 + local;
        u64 cell=0; bool got=false;
        if (fast_ok){
          for (int k=0;k<FAST_TRIES;k++){
            u64 v = load_sc0_u64(pf);
            if ((unsigned)(v>>32) == (unsigned)(q+1)){ cell=v; got=true; break; }
          }
          if (!got) fast_ok = false;
        }
        if (!got){
          int it=0;
          for(;;){ u64 v = aload64(ps);
                   if ((unsigned)(v>>32) == (unsigned)(q+1)){ cell=v; break; }
                   if (++it > CAP){ cell=v; break; } }
        }
        F2U cu; cu.u = (unsigned)cell; hb[p][256+local] = cu.f;
      }
      BAR_LGKM();
    }
  }
}

// ---------------- row-wise log_softmax over 2048, in place ----------------
__global__ __launch_bounds__(256) void logsoftmax_k(float* __restrict__ lp)
{
  const int t = blockIdx.x, lid = threadIdx.x;
  float* row = lp + (size_t)t*2048;
  float4 a = ((const float4*)row)[lid*2];
  float4 b = ((const float4*)row)[lid*2+1];
  float m = fmaxf(fmaxf(fmaxf(a.x,a.y),fmaxf(a.z,a.w)),
                  fmaxf(fmaxf(b.x,b.y),fmaxf(b.z,b.w)));
  #pragma unroll
  for (int off=1; off<64; off<<=1) m = fmaxf(m, __shfl_xor(m, off));
  __shared__ float redm[4], reds[4];
  const int lane = lid & 63, wvi = lid >> 6;
  if (lane==0) redm[wvi] = m;
  __syncthreads();
  m = fmaxf(fmaxf(redm[0],redm[1]), fmaxf(redm[2],redm[3]));
  float s = __expf(a.x-m)+__expf(a.y-m)+__expf(a.z-m)+__expf(a.w-m)
          + __expf(b.x-m)+__expf(b.y-m)+__expf(b.z-m)+__expf(b.w-m);
  #pragma unroll
  for (int off=1; off<64; off<<=1) s += __shfl_xor(s, off);
  if (lane==0) reds[wvi] = s;
  __syncthreads();
  s = reds[0]+reds[1]+reds[2]+reds[3];
  const float lg = m + __logf(s);
  a.x-=lg; a.y-=lg; a.z-=lg; a.w-=lg;
  b.x-=lg; b.y-=lg; b.z-=lg; b.w-=lg;
  ((float4*)row)[lid*2]   = a;
  ((float4*)row)[lid*2+1] = b;
}

// ---------------- values head: one wave per timestep ----------------
__global__ __launch_bounds__(256) void values_k(
    const f16* __restrict__ h1, const float* __restrict__ vW,
    const float* __restrict__ vb, float* __restrict__ outv, int S)
{
  const int gt = (int)((blockIdx.x*256 + threadIdx.x) >> 6);
  if (gt >= S) return;
  const int lane = threadIdx.x & 63;
  const f16* rowp = h1 + (size_t)gt*512;
  float s = 0.f;
  #pragma unroll
  for (int j=0;j<8;j++){
    const int k = lane + (j<<6);
    s += (float)rowp[k] * vW[k];
  }
  #pragma unroll
  for (int off=32; off; off>>=1) s += __shfl_down(s, off);
  if (lane==0) outv[gt] = s + vb[0];
}

extern "C" void kernel_launch(void* const* d_in, const int* in_sizes, int n_in,
                              void* d_out, int out_size, void* d_ws, size_t ws_size,
                              hipStream_t stream) {
  const float* init = (const float*)d_in[0];
  const float* emb  = (const float*)d_in[1];
  const float* Wih0 = (const float*)d_in[2];
  const float* Whh0 = (const float*)d_in[3];
  const float* bih0 = (const float*)d_in[4];
  const float* bhh0 = (const float*)d_in[5];
  const float* Wih1 = (const float*)d_in[6];
  const float* Whh1 = (const float*)d_in[7];
  const float* bih1 = (const float*)d_in[8];
  const float* bhh1 = (const float*)d_in[9];
  const float* actW = (const float*)d_in[10];
  const float* actb = (const float*)d_in[11];
  const float* valW = (const float*)d_in[12];
  const float* valb = (const float*)d_in[13];
  const int*   acts = (const int*)d_in[14];
  const int*   pars = (const int*)d_in[15];
  float* out = (float*)d_out;
  char*  w   = (char*)d_ws;

  f16* h1seq = (f16*)(w + H1SEQ_OFF);
  f16* actWh = (f16*)(w + ACTW_OFF);
  f16* Wih0h = (f16*)(w + WIH0_OFF);
  // d_out overlays (dead before the logits GEMM writes d_out):
  f16* xi0 = (f16*)d_out;                                  // [0,48M)
  f16* X   = (f16*)((char*)d_out + 48u*1024*1024);         // [48M,80M)

  gather_x<<<S_LEN, 256, 0, stream>>>(emb, acts, pars, X);
  cvt_k<<<1536, 256, 0, stream>>>(Wih0, Wih0h, 1536*1024);
  cvt_k<<<1024, 256, 0, stream>>>(actW, actWh, 2048*512);
  init_ctrl<<<1, 256, 0, stream>>>(w);

  // xi0 = X @ W_ih0^T + b_ih0   [S,1536]
  gemm_f16<f16><<<128*12, 256, 0, stream>>>(X, Wih0h, bih0, xi0, S_LEN, 1536, 1024);

  // merged fused two-layer scan
  scan_m<<<128, 768, 0, stream>>>(Whh0, bhh0, Wih1, bih1, Whh1, bhh1,
                                  init, xi0, w);

  // logits = h1seq @ action_W^T + action_b -> d_out, then log_softmax in place
  gemm_f16<float><<<128*16, 256, 0, stream>>>(h1seq, actWh, actb, out, S_LEN, NRULES, 512);
  logsoftmax_k<<<S_LEN, 256, 0, stream>>>(out);
  values_k<<<S_LEN/4, 256, 0, stream>>>(h1seq, valW, valb, out + (size_t)S_LEN*NRULES, S_LEN);
}

// Round 11
// 37687.390 us; speedup vs baseline: 1.4248x; 1.4248x over previous
//
#include <hip/hip_runtime.h>
#include <hip/hip_bf16.h>
#include <hip/hip_fp16.h>

typedef _Float16 f16;
typedef _Float16 f16x2 __attribute__((ext_vector_type(2)));
typedef _Float16 f16x4 __attribute__((ext_vector_type(4)));
typedef _Float16 f16x8 __attribute__((ext_vector_type(8)));
typedef float f32x4 __attribute__((ext_vector_type(4)));
typedef unsigned long long u64;

#define S_LEN 16384
#define NRULES 2048
#define FAST_TRIES 64   // bounded fastcell probe before (sticky) fallback
#define BUDGET 6000000  // cumulative per-thread spin budget (bounded abort)

// ---- ws layout (bytes) ----
#define H1SEQ_OFF 0u                    // 16 MB f16 [S][512]
#define ACTW_OFF  (16u*1024*1024)       // 2 MB f16 action_W
#define WIH0_OFF  (18u*1024*1024)       // 3 MB f16 W_ih0
#define HB0F_OFF  (21u*1024*1024)           // 2*256 u64 fastcells h0 ring
#define HB0S_OFF  (21u*1024*1024 + 4096)    // 2*256 u64 safecells h0 ring
#define HB1F_OFF  (21u*1024*1024 + 8192)    // 2*256 u64 fastcells h1 ring
#define HB1S_OFF  (21u*1024*1024 + 12288)   // 2*256 u64 safecells h1 ring
// d_out overlay: [0,48M) xi0 f16 [S,1536] (live through scan);
//   [48M,80M) X f16 [S,1024] until GEMM0, then FST fast stream (memset);
//   [80M,112M) SST safe stream (memset). Logits GEMM overwrites d_out after.

#if __has_builtin(__builtin_amdgcn_rcpf)
#define RCPF(x) __builtin_amdgcn_rcpf(x)
#else
#define RCPF(x) (1.0f/(x))
#endif

union F2U { f16x2 f; unsigned u; };

__device__ __forceinline__ float sigf(float x){ return RCPF(1.0f + __expf(-x)); }
__device__ __forceinline__ float tanh_fast(float x){
  float ax = fabsf(x);
  float e = __expf(-2.0f*ax);
  float t = (1.0f - e) * RCPF(1.0f + e);
  return x >= 0.0f ? t : -t;
}
__device__ __forceinline__ float dot2(f16x2 a, f16x2 b, float c){
#if __has_builtin(__builtin_amdgcn_fdot2)
  return __builtin_amdgcn_fdot2(a, b, c, false);
#else
  return c + (float)a.x*(float)b.x + (float)a.y*(float)b.y;
#endif
}
// proven authoritative primitives (coherence point):
__device__ __forceinline__ u64 aload64(const u64* p){
  return __hip_atomic_load(p, __ATOMIC_RELAXED, __HIP_MEMORY_SCOPE_AGENT);
}
__device__ __forceinline__ void apub64(u64* p, u64 v){
  (void)__hip_atomic_exchange(p, v, __ATOMIC_RELAXED, __HIP_MEMORY_SCOPE_AGENT);
}
// fast-path primitives (same-XCD L2), proven r7/r8:
__device__ __forceinline__ u64 load_sc0_u64(const u64* p){
  u64 v;
  asm volatile("global_load_dwordx2 %0, %1, off sc0\n\ts_waitcnt vmcnt(0)"
               : "=v"(v) : "v"(p) : "memory");
  return v;
}
__device__ __forceinline__ void store_u64(u64* p, u64 v){
  asm volatile("global_store_dwordx2 %0, %1, off"
               :: "v"(p), "v"(v) : "memory");
}

// ---------------- gather x = [emb[shifted], emb[parent]] as f16 ----------------
__global__ __launch_bounds__(256) void gather_x(
    const float* __restrict__ emb, const int* __restrict__ act,
    const int* __restrict__ par, f16* __restrict__ X)
{
  const int t = blockIdx.x, lid = threadIdx.x;
  const int ia = (t == 0) ? 0 : (act[t-1] + 1);
  const int ip = par[t] + 1;
  const int half = lid >> 7;
  const int k = (lid & 127) << 2;
  const float* src = emb + (size_t)(half ? ip : ia) * 512 + k;
  float4 v = *(const float4*)src;
  f16x4 o; o.x=(f16)v.x; o.y=(f16)v.y; o.z=(f16)v.z; o.w=(f16)v.w;
  *(f16x4*)&X[(size_t)t*1024 + (half<<9) + k] = o;
}

// ---------------- fp32 -> f16 convert ----------------
__global__ __launch_bounds__(256) void cvt_k(const float* __restrict__ in,
                                             f16* __restrict__ out, int n)
{
  const int i = (blockIdx.x*256 + threadIdx.x) << 2;
  if (i >= n) return;
  float4 v = *(const float4*)&in[i];
  f16x4 o; o.x=(f16)v.x; o.y=(f16)v.y; o.z=(f16)v.z; o.w=(f16)v.w;
  *(f16x4*)&out[i] = o;
}

// ---- per-call init: invalidate every ring cell (replay-stale tag safety) ----
__global__ __launch_bounds__(256) void init_ctrl(char* ws)
{
  const int lid = threadIdx.x;
  const u64 inval = (u64)0xF0000000u << 32;   // tag never matched
  u64* F0 = (u64*)(ws + HB0F_OFF);
  u64* S0 = (u64*)(ws + HB0S_OFF);
  u64* F1 = (u64*)(ws + HB1F_OFF);
  u64* S1 = (u64*)(ws + HB1S_OFF);
  F0[lid]=inval; F0[256+lid]=inval;
  S0[lid]=inval; S0[256+lid]=inval;
  F1[lid]=inval; F1[256+lid]=inval;
  S1[lid]=inval; S1[256+lid]=inval;
}

// ---------------- f16 MFMA GEMM: C[M,N] = A[M,K] @ B[N,K]^T + bias ----------------
template<typename OutT>
__global__ __launch_bounds__(256) void gemm_f16(
    const f16* __restrict__ A, const f16* __restrict__ B,
    const float* __restrict__ bias, OutT* __restrict__ C,
    int M, int N, int K)
{
  __shared__ __align__(16) f16 At[4][128][8];
  __shared__ __align__(16) f16 Bt[4][128][8];
  const int lid = threadIdx.x;
  const int mtiles = M >> 7;
  const int bm = blockIdx.x % mtiles;
  const int bn = blockIdx.x / mtiles;
  const int m0 = bm << 7, n0 = bn << 7;
  const int lane = lid & 63, w = lid >> 6;
  const int wm = (w >> 1) << 6, wn = (w & 1) << 6;
  f32x4 acc[4][4] = {};
  const int nk = K >> 5;
  const int row1 = lid >> 2, j1 = lid & 3;
  for (int kt = 0; kt < nk; ++kt){
    const int kb = kt << 5;
    *(f16x8*)&At[j1][row1][0]    = *(const f16x8*)&A[(size_t)(m0+row1)*K    + kb + j1*8];
    *(f16x8*)&At[j1][row1+64][0] = *(const f16x8*)&A[(size_t)(m0+row1+64)*K + kb + j1*8];
    *(f16x8*)&Bt[j1][row1][0]    = *(const f16x8*)&B[(size_t)(n0+row1)*K    + kb + j1*8];
    *(f16x8*)&Bt[j1][row1+64][0] = *(const f16x8*)&B[(size_t)(n0+row1+64)*K + kb + j1*8];
    __syncthreads();
    const int kc = lane >> 4, rr = lane & 15;
    f16x8 aF[4], bF[4];
    #pragma unroll
    for (int m=0;m<4;m++) aF[m] = *(const f16x8*)&At[kc][wm + m*16 + rr][0];
    #pragma unroll
    for (int n=0;n<4;n++) bF[n] = *(const f16x8*)&Bt[kc][wn + n*16 + rr][0];
    #pragma unroll
    for (int m=0;m<4;m++)
      #pragma unroll
      for (int n=0;n<4;n++)
        acc[m][n] = __builtin_amdgcn_mfma_f32_16x16x32_f16(aF[m], bF[n], acc[m][n], 0,0,0);
    __syncthreads();
  }
  const int rr = lane & 15, rg = lane >> 4;
  #pragma unroll
  for (int n=0;n<4;n++){
    const int gcol = n0 + wn + n*16 + rr;
    const float bv = bias[gcol];
    #pragma unroll
    for (int m=0;m<4;m++){
      #pragma unroll
      for (int r=0;r<4;r++){
        const int grow = m0 + wm + m*16 + rg*4 + r;
        C[(size_t)grow*N + gcol] = (OutT)(acc[m][n][r] + bv);
      }
    }
  }
}

// ---- tagged rings, one-XCD + end-of-step poll (publish-BEFORE-poll) ----
// grid=192; participants bid%8==0 -> grp in [0,24): one XCD if round-robin
// (r7-validated). grp 0..7 = ring0 (64 rows, 4 thr/row, Whh0 in VGPRs);
// grp 8..23 = ring1 (32 rows, 8 thr/row, Wih1+Whh1 in VGPRs).
// Invariant (liveness): at step q every block publishes its tag-(q+1) cells
// (fast store AND safe agent-swap) BEFORE any tag-(q+1) poll. Poll sits at
// end-of-step so it absorbs peer skew + publish visibility; stage into
// parity LDS; one __syncthreads (r7-proven) per step end.
// Ring legs: sc0 fast, sticky agent fallback (cells guaranteed published).
// Stream leg (h0->ring1): interleaved sc0+agent, NEVER sticky (not-ready is
// expected while ring0 trails). Cumulative spin budget -> bounded abort.
__global__ __launch_bounds__(256, 1) void scan_rings(
    const float* __restrict__ Whh0, const float* __restrict__ bhh0,
    const float* __restrict__ Wih1, const float* __restrict__ bih1,
    const float* __restrict__ Whh1, const float* __restrict__ bhh1,
    const float* __restrict__ init, const f16* __restrict__ xi0,
    u64* __restrict__ FST, u64* __restrict__ SST, char* ws)
{
  const int lid = threadIdx.x, bid = blockIdx.x;
  if (bid & 7) return;
  const int grp = bid >> 3;
  if (grp >= 24) return;
  f16x2* h1seq = (f16x2*)(ws + H1SEQ_OFF);
  u64* F0 = (u64*)(ws + HB0F_OFF);
  u64* S0 = (u64*)(ws + HB0S_OFF);
  u64* F1 = (u64*)(ws + HB1F_OFF);
  u64* S1 = (u64*)(ws + HB1S_OFF);
  __shared__ f16x2 hxA[2][256];
  __shared__ f16x2 hxB[2][256];
  bool fast_ok = true;
  int budget = BUDGET;

  if (grp < 8){
    // ================= ring0: layer 0 (r7 shape) =================
    const int b = grp;
    const int ksub = lid & 3, row = (b << 6) + (lid >> 2);
    const bool owner = (ksub == 0);
    f16x2 wr[64], wz[64], wn[64];
    #pragma unroll
    for (int i=0;i<64;i++){
      const int k0 = (ksub + (i<<2)) << 1;
      float2 a = *(const float2*)&Whh0[(size_t)row*512         + k0];
      float2 bb= *(const float2*)&Whh0[(size_t)(512+row)*512   + k0];
      float2 c = *(const float2*)&Whh0[(size_t)(1024+row)*512  + k0];
      wr[i].x=(f16)a.x;  wr[i].y=(f16)a.y;
      wz[i].x=(f16)bb.x; wz[i].y=(f16)bb.y;
      wn[i].x=(f16)c.x;  wn[i].y=(f16)c.y;
    }
    float bhr=0.f, bhz=0.f, bhn=0.f, xr=0.f, xz=0.f, xn=0.f;
    if (owner){
      bhr=bhh0[row]; bhz=bhh0[512+row]; bhn=bhh0[1024+row];
      xr=(float)xi0[row]; xz=(float)xi0[512+row]; xn=(float)xi0[1024+row];
    }
    { F2U s; s.f.x=(f16)init[2*lid]; s.f.y=(f16)init[2*lid+1]; hxA[0][lid]=s.f; }
    __syncthreads();

    for (int q=0; q<S_LEN; ++q){
      const int p = (q+1)&1;
      const f16x2* cur = hxA[q&1];
      float ar=0.f, az=0.f, an=0.f;
      #pragma unroll
      for (int i=0;i<64;i++){
        f16x2 hv = cur[ksub + (i<<2)];
        ar = dot2(wr[i],hv,ar); az = dot2(wz[i],hv,az); an = dot2(wn[i],hv,an);
      }
      ar += __shfl_xor(ar,1); ar += __shfl_xor(ar,2);
      az += __shfl_xor(az,1); az += __shfl_xor(az,2);
      an += __shfl_xor(an,1); an += __shfl_xor(an,2);
      float hnew = 0.f;
      if (owner){
        float r_ = sigf(xr + ar + bhr);
        float z_ = sigf(xz + az + bhz);
        float nl = tanh_fast(xn + r_*(an + bhn));
        hnew = (1.0f - z_)*nl + z_*(float)cur[row>>1][row&1];
      }
      float hp = __shfl(hnew, (lid & 192) + ((lid+4) & 63));
      // ---- publish EVERYTHING (fast + safe) before any poll ----
      if ((lid & 7) == 0){
        F2U pr; pr.f.x=(f16)hnew; pr.f.y=(f16)hp;
        const int j = (b<<5) + (lid>>3);
        const u64 tg = ((u64)(unsigned)(q+1)<<32) | (u64)pr.u;
        store_u64(&F0[p*256 + j], tg);
        store_u64(&FST[(size_t)q*256 + j], tg);
        apub64(&S0[p*256 + j], tg);
        apub64(&SST[(size_t)q*256 + j], tg);
      }
      if (owner && q+1 < S_LEN){       // xi prefetch rides the poll spin
        const f16* xp = xi0 + (size_t)(q+1)*1536;
        xr=(float)xp[row]; xz=(float)xp[512+row]; xn=(float)xp[1024+row];
      }
      // ---- end-of-step poll: tag q+1 (all publishes for it already issued) ----
      if (q+1 < S_LEN){
        const u64* pf = F0 + p*256 + lid;
        const u64* ps = S0 + p*256 + lid;
        u64 cell=0; bool got=false;
        if (fast_ok){
          for (int k=0;k<FAST_TRIES;k++){
            u64 v = load_sc0_u64(pf);
            if ((unsigned)(v>>32) == (unsigned)(q+1)){ cell=v; got=true; break; }
          }
          if (!got) fast_ok = false;   // ring cells guaranteed published
        }
        if (!got){
          for(;;){ u64 v = aload64(ps);
                   if ((unsigned)(v>>32) == (unsigned)(q+1)){ cell=v; break; }
                   if (--budget < 0){ cell=v; break; } }
        }
        F2U cu; cu.u = (unsigned)cell; hxA[p][lid] = cu.f;
      }
      __syncthreads();
    }
  } else {
    // ================= ring1: layer 1 (r7 shape) =================
    const int u = grp - 8;
    const int ksub = lid & 7, row = (u << 5) + (lid >> 3);
    const bool owner = (ksub == 0);
    f16x2 ur[32], uz[32], un[32], vr[32], vz[32], vn[32];
    #pragma unroll
    for (int i=0;i<32;i++){
      const int k0 = (ksub + (i<<3)) << 1;
      float2 a = *(const float2*)&Wih1[(size_t)row*512        + k0];
      float2 bb= *(const float2*)&Wih1[(size_t)(512+row)*512  + k0];
      float2 c = *(const float2*)&Wih1[(size_t)(1024+row)*512 + k0];
      float2 d = *(const float2*)&Whh1[(size_t)row*512        + k0];
      float2 e = *(const float2*)&Whh1[(size_t)(512+row)*512  + k0];
      float2 f = *(const float2*)&Whh1[(size_t)(1024+row)*512 + k0];
      ur[i].x=(f16)a.x;  ur[i].y=(f16)a.y;
      uz[i].x=(f16)bb.x; uz[i].y=(f16)bb.y;
      un[i].x=(f16)c.x;  un[i].y=(f16)c.y;
      vr[i].x=(f16)d.x;  vr[i].y=(f16)d.y;
      vz[i].x=(f16)e.x;  vz[i].y=(f16)e.y;
      vn[i].x=(f16)f.x;  vn[i].y=(f16)f.y;
    }
    float bir=0.f,biz=0.f,bin=0.f, bhr=0.f,bhz=0.f,bhn=0.f;
    if (owner){
      bir=bih1[row]; biz=bih1[512+row]; bin=bih1[1024+row];
      bhr=bhh1[row]; bhz=bhh1[512+row]; bhn=bhh1[1024+row];
    }
    { F2U s; s.f.x=(f16)init[512+2*lid]; s.f.y=(f16)init[512+2*lid+1]; hxB[0][lid]=s.f; }
    {  // initial: h0[0] from stream (tag 1) — interleaved, never sticky
      const u64* pf = FST + lid;
      const u64* ps = SST + lid;
      u64 cell=0;
      for(;;){
        u64 v = load_sc0_u64(pf);
        if ((unsigned)(v>>32) == 1u){ cell=v; break; }
        v = aload64(ps);
        if ((unsigned)(v>>32) == 1u){ cell=v; break; }
        if (--budget < 0){ cell=v; break; }
      }
      F2U cu; cu.u = (unsigned)cell; hxA[0][lid] = cu.f;
    }
    __syncthreads();

    for (int t=0; t<S_LEN; ++t){
      const int p = (t+1)&1;
      const f16x2* xcur = hxA[t&1];
      const f16x2* hcur = hxB[t&1];
      float ir=0.f, iz=0.f, in_=0.f, hr=0.f, hz=0.f, hn=0.f;
      #pragma unroll
      for (int i=0;i<32;i++){
        f16x2 xv = xcur[ksub + (i<<3)];
        f16x2 hv = hcur[ksub + (i<<3)];
        ir = dot2(ur[i],xv,ir); iz = dot2(uz[i],xv,iz); in_ = dot2(un[i],xv,in_);
        hr = dot2(vr[i],hv,hr); hz = dot2(vz[i],hv,hz); hn  = dot2(vn[i],hv,hn);
      }
      #pragma unroll
      for (int d=1; d<8; d<<=1){
        ir += __shfl_xor(ir,d); iz += __shfl_xor(iz,d); in_ += __shfl_xor(in_,d);
        hr += __shfl_xor(hr,d); hz += __shfl_xor(hz,d); hn  += __shfl_xor(hn,d);
      }
      float hnew = 0.f;
      if (owner){
        float r_ = sigf(ir + bir + hr + bhr);
        float z_ = sigf(iz + biz + hz + bhz);
        float nl = tanh_fast(in_ + bin + r_*(hn + bhn));
        hnew = (1.0f - z_)*nl + z_*(float)hcur[row>>1][row&1];
      }
      float hp = __shfl(hnew, (lid & 192) + ((lid+8) & 63));
      // ---- publish (fast + safe) before any poll ----
      if ((lid & 15) == 0){
        F2U pr; pr.f.x=(f16)hnew; pr.f.y=(f16)hp;
        const int j = (u<<4) + (lid>>4);
        const u64 tg = ((u64)(unsigned)(t+1)<<32) | (u64)pr.u;
        store_u64(&F1[p*256 + j], tg);
        apub64(&S1[p*256 + j], tg);
        h1seq[(size_t)t*256 + j] = pr.f;   // plain; read post-kernel
      }
      // ---- end-of-step polls ----
      if (t+1 < S_LEN){
        const u64* pfA = FST + (size_t)(t+1)*256 + lid;   // stream: tag t+2
        const u64* psA = SST + (size_t)(t+1)*256 + lid;
        const u64* pfB = F1 + p*256 + lid;                // ring: tag t+1
        const u64* psB = S1 + p*256 + lid;
        u64 ca=0, cb=0; bool ga=false, gb=false;
        if (fast_ok){
          for (int k=0; k<FAST_TRIES && !gb; ++k){
            u64 v = load_sc0_u64(pfB);
            if ((unsigned)(v>>32) == (unsigned)(t+1)){ cb=v; gb=true; }
            if (!ga){
              v = load_sc0_u64(pfA);
              if ((unsigned)(v>>32) == (unsigned)(t+2)){ ca=v; ga=true; }
            }
          }
          if (!gb) fast_ok = false;    // ring leg guaranteed published
        }
        while (!(ga && gb)){
          if (!ga){
            if (fast_ok){
              u64 v = load_sc0_u64(pfA);
              if ((unsigned)(v>>32) == (unsigned)(t+2)){ ca=v; ga=true; }
            }
            if (!ga){
              u64 v = aload64(psA);
              if ((unsigned)(v>>32) == (unsigned)(t+2)){ ca=v; ga=true; }
            }
          }
          if (!gb){
            u64 v = aload64(psB);
            if ((unsigned)(v>>32) == (unsigned)(t+1)){ cb=v; gb=true; }
          }
          if (--budget < 0) break;
        }
        F2U xa; xa.u = (unsigned)ca; hxA[p][lid] = xa.f;
        F2U hb; hb.u = (unsigned)cb; hxB[p][lid] = hb.f;
      }
      __syncthreads();
    }
  }
}

// ---------------- row-wise log_softmax over 2048, in place ----------------
__global__ __launch_bounds__(256) void logsoftmax_k(float* __restrict__ lp)
{
  const int t = blockIdx.x, lid = threadIdx.x;
  float* row = lp + (size_t)t*2048;
  float4 a = ((const float4*)row)[lid*2];
  float4 b = ((const float4*)row)[lid*2+1];
  float m = fmaxf(fmaxf(fmaxf(a.x,a.y),fmaxf(a.z,a.w)),
                  fmaxf(fmaxf(b.x,b.y),fmaxf(b.z,b.w)));
  #pragma unroll
  for (int off=1; off<64; off<<=1) m = fmaxf(m, __shfl_xor(m, off));
  __shared__ float redm[4], reds[4];
  const int lane = lid & 63, wvi = lid >> 6;
  if (lane==0) redm[wvi] = m;
  __syncthreads();
  m = fmaxf(fmaxf(redm[0],redm[1]), fmaxf(redm[2],redm[3]));
  float s = __expf(a.x-m)+__expf(a.y-m)+__expf(a.z-m)+__expf(a.w-m)
          + __expf(b.x-m)+__expf(b.y-m)+__expf(b.z-m)+__expf(b.w-m);
  #pragma unroll
  for (int off=1; off<64; off<<=1) s += __shfl_xor(s, off);
  if (lane==0) reds[wvi] = s;
  __syncthreads();
  s = reds[0]+reds[1]+reds[2]+reds[3];
  const float lg = m + __logf(s);
  a.x-=lg; a.y-=lg; a.z-=lg; a.w-=lg;
  b.x-=lg; b.y-=lg; b.z-=lg; b.w-=lg;
  ((float4*)row)[lid*2]   = a;
  ((float4*)row)[lid*2+1] = b;
}

// ---------------- values head: one wave per timestep ----------------
__global__ __launch_bounds__(256) void values_k(
    const f16* __restrict__ h1, const float* __restrict__ vW,
    const float* __restrict__ vb, float* __restrict__ outv, int S)
{
  const int gt = (int)((blockIdx.x*256 + threadIdx.x) >> 6);
  if (gt >= S) return;
  const int lane = threadIdx.x & 63;
  const f16* rowp = h1 + (size_t)gt*512;
  float s = 0.f;
  #pragma unroll
  for (int j=0;j<8;j++){
    const int k = lane + (j<<6);
    s += (float)rowp[k] * vW[k];
  }
  #pragma unroll
  for (int off=32; off; off>>=1) s += __shfl_down(s, off);
  if (lane==0) outv[gt] = s + vb[0];
}

extern "C" void kernel_launch(void* const* d_in, const int* in_sizes, int n_in,
                              void* d_out, int out_size, void* d_ws, size_t ws_size,
                              hipStream_t stream) {
  const float* init = (const float*)d_in[0];
  const float* emb  = (const float*)d_in[1];
  const float* Wih0 = (const float*)d_in[2];
  const float* Whh0 = (const float*)d_in[3];
  const float* bih0 = (const float*)d_in[4];
  const float* bhh0 = (const float*)d_in[5];
  const float* Wih1 = (const float*)d_in[6];
  const float* Whh1 = (const float*)d_in[7];
  const float* bih1 = (const float*)d_in[8];
  const float* bhh1 = (const float*)d_in[9];
  const float* actW = (const float*)d_in[10];
  const float* actb = (const float*)d_in[11];
  const float* valW = (const float*)d_in[12];
  const float* valb = (const float*)d_in[13];
  const int*   acts = (const int*)d_in[14];
  const int*   pars = (const int*)d_in[15];
  float* out = (float*)d_out;
  char*  w   = (char*)d_ws;

  f16* h1seq = (f16*)(w + H1SEQ_OFF);
  f16* actWh = (f16*)(w + ACTW_OFF);
  f16* Wih0h = (f16*)(w + WIH0_OFF);
  // d_out overlays (all dead before the logits GEMM writes d_out):
  f16* xi0 = (f16*)d_out;                                  // [0,48M)
  f16* X   = (f16*)((char*)d_out + 48u*1024*1024);         // [48M,80M)
  u64* FST = (u64*)((char*)d_out + 48u*1024*1024);         // [48M,80M) after GEMM0
  u64* SST = (u64*)((char*)d_out + 80u*1024*1024);         // [80M,112M)

  gather_x<<<S_LEN, 256, 0, stream>>>(emb, acts, pars, X);
  cvt_k<<<1536, 256, 0, stream>>>(Wih0, Wih0h, 1536*1024);
  cvt_k<<<1024, 256, 0, stream>>>(actW, actWh, 2048*512);
  init_ctrl<<<1, 256, 0, stream>>>(w);

  // xi0 = X @ W_ih0^T + b_ih0   [S,1536]
  gemm_f16<f16><<<128*12, 256, 0, stream>>>(X, Wih0h, bih0, xi0, S_LEN, 1536, 1024);

  // X is now dead: clear both stream buffers' tags, then run the scan
  hipMemsetAsync(FST, 0, (size_t)S_LEN*256*8, stream);
  hipMemsetAsync(SST, 0, (size_t)S_LEN*256*8, stream);
  scan_rings<<<192, 256, 0, stream>>>(Whh0, bhh0, Wih1, bih1, Whh1, bhh1,
                                      init, xi0, FST, SST, w);

  // logits = h1seq @ action_W^T + action_b -> d_out, then log_softmax in place
  gemm_f16<float><<<128*16, 256, 0, stream>>>(h1seq, actWh, actb, out, S_LEN, NRULES, 512);
  logsoftmax_k<<<S_LEN, 256, 0, stream>>>(out);
  values_k<<<S_LEN/4, 256, 0, stream>>>(h1seq, valW, valb, out + (size_t)S_LEN*NRULES, S_LEN);
}

// Round 12
// 33054.520 us; speedup vs baseline: 1.6245x; 1.1402x over previous
//
#include <hip/hip_runtime.h>
#include <hip/hip_bf16.h>
#include <hip/hip_fp16.h>

typedef _Float16 f16;
typedef _Float16 f16x2 __attribute__((ext_vector_type(2)));
typedef _Float16 f16x4 __attribute__((ext_vector_type(4)));
typedef _Float16 f16x8 __attribute__((ext_vector_type(8)));
typedef float f32x4 __attribute__((ext_vector_type(4)));
typedef unsigned long long u64;

#define S_LEN 16384
#define NRULES 2048
#define FAST_TRIES 64   // bounded fastcell probe before fallback (pre-disable)
#define BUDGET 2000000  // cumulative per-thread spin budget (bounded abort)
#define VOTE_STEP   64  // publish per-block fast-health vote
#define READ_STEP   97  // read all votes
#define FREE_STEP  128  // unanimously drop safecell swaps

// ---- ws layout (bytes) ----
#define H1SEQ_OFF 0u                    // 16 MB f16 [S][512]
#define ACTW_OFF  (16u*1024*1024)       // 2 MB f16 action_W
#define WIH0_OFF  (18u*1024*1024)       // 3 MB f16 W_ih0
#define HB0F_OFF  (21u*1024*1024)           // 2*256 u64 fastcells h0 ring
#define HB0S_OFF  (21u*1024*1024 + 4096)    // 2*256 u64 safecells h0 ring
#define HB1F_OFF  (21u*1024*1024 + 8192)    // 2*256 u64 fastcells h1 ring
#define HB1S_OFF  (21u*1024*1024 + 12288)   // 2*256 u64 safecells h1 ring
#define VOTE_OFF  (21u*1024*1024 + 16384)   // 32 u64 vote cells
// d_out overlay: [0,48M) xi0 f16 [S,1536] (live through scan);
//   [48M,80M) X f16 [S,1024] until GEMM0, then FST fast stream (memset);
//   [80M,112M) SST safe stream (memset). Logits GEMM overwrites d_out after.

#if __has_builtin(__builtin_amdgcn_rcpf)
#define RCPF(x) __builtin_amdgcn_rcpf(x)
#else
#define RCPF(x) (1.0f/(x))
#endif

union F2U { f16x2 f; unsigned u; };
union H8  { f16x8 v; f16x2 p[4]; };

__device__ __forceinline__ float sigf(float x){ return RCPF(1.0f + __expf(-x)); }
__device__ __forceinline__ float tanh_fast(float x){
  float ax = fabsf(x);
  float e = __expf(-2.0f*ax);
  float t = (1.0f - e) * RCPF(1.0f + e);
  return x >= 0.0f ? t : -t;
}
__device__ __forceinline__ float dot2(f16x2 a, f16x2 b, float c){
#if __has_builtin(__builtin_amdgcn_fdot2)
  return __builtin_amdgcn_fdot2(a, b, c, false);
#else
  return c + (float)a.x*(float)b.x + (float)a.y*(float)b.y;
#endif
}
// proven authoritative primitives (coherence point):
__device__ __forceinline__ u64 aload64(const u64* p){
  return __hip_atomic_load(p, __ATOMIC_RELAXED, __HIP_MEMORY_SCOPE_AGENT);
}
__device__ __forceinline__ void apub64(u64* p, u64 v){
  (void)__hip_atomic_exchange(p, v, __ATOMIC_RELAXED, __HIP_MEMORY_SCOPE_AGENT);
}
// fast-path primitives (same-XCD L2), proven r7/r8/r11:
__device__ __forceinline__ u64 load_sc0_u64(const u64* p){
  u64 v;
  asm volatile("global_load_dwordx2 %0, %1, off sc0\n\ts_waitcnt vmcnt(0)"
               : "=v"(v) : "v"(p) : "memory");
  return v;
}
__device__ __forceinline__ void store_u64(u64* p, u64 v){
  asm volatile("global_store_dwordx2 %0, %1, off"
               :: "v"(p), "v"(v) : "memory");
}
// LDS-only barrier (drains lgkm, NOT vmcnt) — publishes stay in flight.
#define BAR_LGKM() asm volatile("s_waitcnt lgkmcnt(0)\n\ts_barrier" ::: "memory")

// ---------------- gather x = [emb[shifted], emb[parent]] as f16 ----------------
__global__ __launch_bounds__(256) void gather_x(
    const float* __restrict__ emb, const int* __restrict__ act,
    const int* __restrict__ par, f16* __restrict__ X)
{
  const int t = blockIdx.x, lid = threadIdx.x;
  const int ia = (t == 0) ? 0 : (act[t-1] + 1);
  const int ip = par[t] + 1;
  const int half = lid >> 7;
  const int k = (lid & 127) << 2;
  const float* src = emb + (size_t)(half ? ip : ia) * 512 + k;
  float4 v = *(const float4*)src;
  f16x4 o; o.x=(f16)v.x; o.y=(f16)v.y; o.z=(f16)v.z; o.w=(f16)v.w;
  *(f16x4*)&X[(size_t)t*1024 + (half<<9) + k] = o;
}

// ---------------- fp32 -> f16 convert ----------------
__global__ __launch_bounds__(256) void cvt_k(const float* __restrict__ in,
                                             f16* __restrict__ out, int n)
{
  const int i = (blockIdx.x*256 + threadIdx.x) << 2;
  if (i >= n) return;
  float4 v = *(const float4*)&in[i];
  f16x4 o; o.x=(f16)v.x; o.y=(f16)v.y; o.z=(f16)v.z; o.w=(f16)v.w;
  *(f16x4*)&out[i] = o;
}

// ---- per-call init: invalidate ring cells + zero votes ----
__global__ __launch_bounds__(256) void init_ctrl(char* ws)
{
  const int lid = threadIdx.x;
  const u64 inval = (u64)0xF0000000u << 32;   // tag never matched
  u64* F0 = (u64*)(ws + HB0F_OFF);
  u64* S0 = (u64*)(ws + HB0S_OFF);
  u64* F1 = (u64*)(ws + HB1F_OFF);
  u64* S1 = (u64*)(ws + HB1S_OFF);
  u64* V  = (u64*)(ws + VOTE_OFF);
  F0[lid]=inval; F0[256+lid]=inval;
  S0[lid]=inval; S0[256+lid]=inval;
  F1[lid]=inval; F1[256+lid]=inval;
  S1[lid]=inval; S1[256+lid]=inval;
  if (lid < 32) V[lid] = 0;
}

// ---------------- f16 MFMA GEMM: C[M,N] = A[M,K] @ B[N,K]^T + bias ----------------
template<typename OutT>
__global__ __launch_bounds__(256) void gemm_f16(
    const f16* __restrict__ A, const f16* __restrict__ B,
    const float* __restrict__ bias, OutT* __restrict__ C,
    int M, int N, int K)
{
  __shared__ __align__(16) f16 At[4][128][8];
  __shared__ __align__(16) f16 Bt[4][128][8];
  const int lid = threadIdx.x;
  const int mtiles = M >> 7;
  const int bm = blockIdx.x % mtiles;
  const int bn = blockIdx.x / mtiles;
  const int m0 = bm << 7, n0 = bn << 7;
  const int lane = lid & 63, w = lid >> 6;
  const int wm = (w >> 1) << 6, wn = (w & 1) << 6;
  f32x4 acc[4][4] = {};
  const int nk = K >> 5;
  const int row1 = lid >> 2, j1 = lid & 3;
  for (int kt = 0; kt < nk; ++kt){
    const int kb = kt << 5;
    *(f16x8*)&At[j1][row1][0]    = *(const f16x8*)&A[(size_t)(m0+row1)*K    + kb + j1*8];
    *(f16x8*)&At[j1][row1+64][0] = *(const f16x8*)&A[(size_t)(m0+row1+64)*K + kb + j1*8];
    *(f16x8*)&Bt[j1][row1][0]    = *(const f16x8*)&B[(size_t)(n0+row1)*K    + kb + j1*8];
    *(f16x8*)&Bt[j1][row1+64][0] = *(const f16x8*)&B[(size_t)(n0+row1+64)*K + kb + j1*8];
    __syncthreads();
    const int kc = lane >> 4, rr = lane & 15;
    f16x8 aF[4], bF[4];
    #pragma unroll
    for (int m=0;m<4;m++) aF[m] = *(const f16x8*)&At[kc][wm + m*16 + rr][0];
    #pragma unroll
    for (int n=0;n<4;n++) bF[n] = *(const f16x8*)&Bt[kc][wn + n*16 + rr][0];
    #pragma unroll
    for (int m=0;m<4;m++)
      #pragma unroll
      for (int n=0;n<4;n++)
        acc[m][n] = __builtin_amdgcn_mfma_f32_16x16x32_f16(aF[m], bF[n], acc[m][n], 0,0,0);
    __syncthreads();
  }
  const int rr = lane & 15, rg = lane >> 4;
  #pragma unroll
  for (int n=0;n<4;n++){
    const int gcol = n0 + wn + n*16 + rr;
    const float bv = bias[gcol];
    #pragma unroll
    for (int m=0;m<4;m++){
      #pragma unroll
      for (int r=0;r<4;r++){
        const int grow = m0 + wm + m*16 + rg*4 + r;
        C[(size_t)grow*N + gcol] = (OutT)(acc[m][n][r] + bv);
      }
    }
  }
}

// ---- tagged rings: perm-LDS vectorized + verified swap self-disable ----
// grid=192; participants bid%8==0 -> grp in [0,24) (one XCD if round-robin,
// r7-validated). grp 0..7 = ring0 (64 rows, 4 thr/row); grp 8..23 = ring1
// (32 rows, 8 thr/row, Wih1+Whh1). Protocol = r11 (publish-before-poll,
// proven live) for steps < FREE_STEP. Steps 0..63 record whether any
// safe-path catch was sc0-INVISIBLE (verify re-probe); step 64 each block
// votes (agent swap); step 97 all read votes; step >=128: if unanimous
// fast-health, drop all safecell swaps -> polls wait only on L2 stores.
// LDS is PERMUTED: pair j lives at [j%T][j/T] so each thread's dot operands
// are contiguous -> ds_read_b128 (broadcast across same-ksub lanes).
__global__ __launch_bounds__(256, 1) void scan_rings(
    const float* __restrict__ Whh0, const float* __restrict__ bhh0,
    const float* __restrict__ Wih1, const float* __restrict__ bih1,
    const float* __restrict__ Whh1, const float* __restrict__ bhh1,
    const float* __restrict__ init, const f16* __restrict__ xi0,
    u64* __restrict__ FST, u64* __restrict__ SST, char* ws)
{
  const int lid = threadIdx.x, bid = blockIdx.x;
  if (bid & 7) return;
  const int grp = bid >> 3;
  if (grp >= 24) return;
  f16x2* h1seq = (f16x2*)(ws + H1SEQ_OFF);
  u64* F0 = (u64*)(ws + HB0F_OFF);
  u64* S0 = (u64*)(ws + HB0S_OFF);
  u64* F1 = (u64*)(ws + HB1F_OFF);
  u64* S1 = (u64*)(ws + HB1S_OFF);
  u64* VOTE = (u64*)(ws + VOTE_OFF);
  __shared__ __align__(16) f16x2 shA[2][256];
  __shared__ __align__(16) f16x2 shB[2][256];
  __shared__ int s_bad, s_keep;
  if (lid == 0){ s_bad = 0; s_keep = 0; }
  bool fast_ok = true;
  bool my_bad = false;    // verified sc0-invisibility observed (steps 0..63)
  int budget = BUDGET;

  if (grp < 8){
    // ================= ring0: layer 0 =================
    const int b = grp;
    const int ksub = lid & 3, row = (b << 6) + (lid >> 2);
    const bool owner = (ksub == 0);
    f16x2 wr[64], wz[64], wn[64];
    #pragma unroll
    for (int i=0;i<64;i++){
      const int k0 = (ksub + (i<<2)) << 1;
      float2 a = *(const float2*)&Whh0[(size_t)row*512         + k0];
      float2 bb= *(const float2*)&Whh0[(size_t)(512+row)*512   + k0];
      float2 c = *(const float2*)&Whh0[(size_t)(1024+row)*512  + k0];
      wr[i].x=(f16)a.x;  wr[i].y=(f16)a.y;
      wz[i].x=(f16)bb.x; wz[i].y=(f16)bb.y;
      wn[i].x=(f16)c.x;  wn[i].y=(f16)c.y;
    }
    float bhr=0.f, bhz=0.f, bhn=0.f, xr=0.f, xz=0.f, xn=0.f;
    if (owner){
      bhr=bhh0[row]; bhz=bhh0[512+row]; bhn=bhh0[1024+row];
      xr=(float)xi0[row]; xz=(float)xi0[512+row]; xn=(float)xi0[1024+row];
    }
    { // seed: pair lid -> perm slot
      F2U s; s.f.x=(f16)init[2*lid]; s.f.y=(f16)init[2*lid+1];
      shA[0][(lid&3)*64 + (lid>>2)] = s.f;
    }
    BAR_LGKM();

    for (int q=0; q<S_LEN; ++q){
      const int p = (q+1)&1;
      if (q == VOTE_STEP && lid == 0) apub64(&VOTE[b], s_bad ? 2u : 1u);
      if (q == READ_STEP && lid < 24){
        u64 v = aload64(&VOTE[lid]); if (v != 1u) s_keep = 1;
      }
      const bool noswap = (q >= FREE_STEP) && (s_keep == 0);
      // ---- compute (vectorized LDS reads) ----
      const f16x2* hbase = &shA[q&1][ksub*64];
      float ar=0.f, az=0.f, an=0.f;
      #pragma unroll
      for (int i4=0;i4<16;i4++){
        H8 h; h.v = *(const f16x8*)&hbase[i4*4];
        #pragma unroll
        for (int m=0;m<4;m++){
          const int i = i4*4+m;
          ar = dot2(wr[i],h.p[m],ar); az = dot2(wz[i],h.p[m],az); an = dot2(wn[i],h.p[m],an);
        }
      }
      ar += __shfl_xor(ar,1); ar += __shfl_xor(ar,2);
      az += __shfl_xor(az,1); az += __shfl_xor(az,2);
      an += __shfl_xor(an,1); an += __shfl_xor(an,2);
      float hnew = 0.f;
      if (owner){
        const int j = row>>1;
        f16x2 pr2 = shA[q&1][(j&3)*64 + (j>>2)];
        float h_old = (row&1) ? (float)pr2.y : (float)pr2.x;
        float r_ = sigf(xr + ar + bhr);
        float z_ = sigf(xz + az + bhz);
        float nl = tanh_fast(xn + r_*(an + bhn));
        hnew = (1.0f - z_)*nl + z_*h_old;
      }
      float hp = __shfl(hnew, (lid & 192) + ((lid+4) & 63));
      // ---- publish before poll (liveness invariant) ----
      if ((lid & 7) == 0){
        F2U pr; pr.f.x=(f16)hnew; pr.f.y=(f16)hp;
        const int j = (b<<5) + (lid>>3);
        const u64 tg = ((u64)(unsigned)(q+1)<<32) | (u64)pr.u;
        store_u64(&F0[p*256 + j], tg);
        store_u64(&FST[(size_t)q*256 + j], tg);
        if (!noswap){
          apub64(&S0[p*256 + j], tg);
          apub64(&SST[(size_t)q*256 + j], tg);
        }
      }
      if (owner && q+1 < S_LEN){       // xi prefetch rides the poll spin
        const f16* xp = xi0 + (size_t)(q+1)*1536;
        xr=(float)xp[row]; xz=(float)xp[512+row]; xn=(float)xp[1024+row];
      }
      // ---- end-of-step poll: tag q+1 ----
      if (q+1 < S_LEN){
        const u64* pf = F0 + p*256 + lid;
        const u64* ps = S0 + p*256 + lid;
        u64 cell=0;
        if (noswap){
          for(;;){ u64 v = load_sc0_u64(pf);
                   if ((unsigned)(v>>32) == (unsigned)(q+1)){ cell=v; break; }
                   if (--budget < 0){ cell=v; break; } }
        } else {
          bool got = false;
          if (fast_ok){
            for (int k=0;k<FAST_TRIES;k++){
              u64 v = load_sc0_u64(pf);
              if ((unsigned)(v>>32) == (unsigned)(q+1)){ cell=v; got=true; break; }
            }
            if (!got) fast_ok = false;
          }
          if (!got){
            for(;;){ u64 v = aload64(ps);
                     if ((unsigned)(v>>32) == (unsigned)(q+1)){ cell=v; break; }
                     if (--budget < 0){ cell=v; break; } }
            if (q < VOTE_STEP){        // verify: is the fast cell sc0-visible?
              u64 v = load_sc0_u64(pf);
              if ((unsigned)(v>>32) != (unsigned)(q+1)) my_bad = true;
            }
          }
        }
        F2U cu; cu.u = (unsigned)cell;
        shA[p][(lid&3)*64 + (lid>>2)] = cu.f;
      }
      if (q == VOTE_STEP-1 && my_bad) s_bad = 1;
      BAR_LGKM();
    }
  } else {
    // ================= ring1: layer 1 =================
    const int u = grp - 8;
    const int ksub = lid & 7, row = (u << 5) + (lid >> 3);
    const bool owner = (ksub == 0);
    f16x2 ur[32], uz[32], un[32], vr[32], vz[32], vn[32];
    #pragma unroll
    for (int i=0;i<32;i++){
      const int k0 = (ksub + (i<<3)) << 1;
      float2 a = *(const float2*)&Wih1[(size_t)row*512        + k0];
      float2 bb= *(const float2*)&Wih1[(size_t)(512+row)*512  + k0];
      float2 c = *(const float2*)&Wih1[(size_t)(1024+row)*512 + k0];
      float2 d = *(const float2*)&Whh1[(size_t)row*512        + k0];
      float2 e = *(const float2*)&Whh1[(size_t)(512+row)*512  + k0];
      float2 f = *(const float2*)&Whh1[(size_t)(1024+row)*512 + k0];
      ur[i].x=(f16)a.x;  ur[i].y=(f16)a.y;
      uz[i].x=(f16)bb.x; uz[i].y=(f16)bb.y;
      un[i].x=(f16)c.x;  un[i].y=(f16)c.y;
      vr[i].x=(f16)d.x;  vr[i].y=(f16)d.y;
      vz[i].x=(f16)e.x;  vz[i].y=(f16)e.y;
      vn[i].x=(f16)f.x;  vn[i].y=(f16)f.y;
    }
    float bir=0.f,biz=0.f,bin=0.f, bhr=0.f,bhz=0.f,bhn=0.f;
    if (owner){
      bir=bih1[row]; biz=bih1[512+row]; bin=bih1[1024+row];
      bhr=bhh1[row]; bhz=bhh1[512+row]; bhn=bhh1[1024+row];
    }
    { F2U s; s.f.x=(f16)init[512+2*lid]; s.f.y=(f16)init[512+2*lid+1];
      shB[0][(lid&7)*32 + (lid>>3)] = s.f; }
    {  // initial: h0[0] from stream (tag 1) — interleaved, never sticky
      const u64* pf = FST + lid;
      const u64* ps = SST + lid;
      u64 cell=0;
      for(;;){
        u64 v = load_sc0_u64(pf);
        if ((unsigned)(v>>32) == 1u){ cell=v; break; }
        v = aload64(ps);
        if ((unsigned)(v>>32) == 1u){
          cell=v;
          u64 vv = load_sc0_u64(pf);
          if ((unsigned)(vv>>32) != 1u) my_bad = true;
          break;
        }
        if (--budget < 0){ cell=v; break; }
      }
      F2U cu; cu.u = (unsigned)cell; shA[0][(lid&7)*32 + (lid>>3)] = cu.f;
    }
    BAR_LGKM();

    for (int t=0; t<S_LEN; ++t){
      const int p = (t+1)&1;
      if (t == VOTE_STEP && lid == 0) apub64(&VOTE[grp], s_bad ? 2u : 1u);
      if (t == READ_STEP && lid < 24){
        u64 v = aload64(&VOTE[lid]); if (v != 1u) s_keep = 1;
      }
      const bool noswap = (t >= FREE_STEP) && (s_keep == 0);
      // ---- compute (vectorized LDS reads) ----
      const f16x2* xbase = &shA[t&1][ksub*32];
      const f16x2* hbase = &shB[t&1][ksub*32];
      float ir=0.f, iz=0.f, in_=0.f, hr=0.f, hz=0.f, hn=0.f;
      #pragma unroll
      for (int i4=0;i4<8;i4++){
        H8 hx; hx.v = *(const f16x8*)&xbase[i4*4];
        H8 hh; hh.v = *(const f16x8*)&hbase[i4*4];
        #pragma unroll
        for (int m=0;m<4;m++){
          const int i = i4*4+m;
          ir = dot2(ur[i],hx.p[m],ir); iz = dot2(uz[i],hx.p[m],iz); in_ = dot2(un[i],hx.p[m],in_);
          hr = dot2(vr[i],hh.p[m],hr); hz = dot2(vz[i],hh.p[m],hz); hn  = dot2(vn[i],hh.p[m],hn);
        }
      }
      #pragma unroll
      for (int d=1; d<8; d<<=1){
        ir += __shfl_xor(ir,d); iz += __shfl_xor(iz,d); in_ += __shfl_xor(in_,d);
        hr += __shfl_xor(hr,d); hz += __shfl_xor(hz,d); hn  += __shfl_xor(hn,d);
      }
      float hnew = 0.f;
      if (owner){
        const int j = row>>1;
        f16x2 pr2 = shB[t&1][(j&7)*32 + (j>>3)];
        float h_old = (row&1) ? (float)pr2.y : (float)pr2.x;
        float r_ = sigf(ir + bir + hr + bhr);
        float z_ = sigf(iz + biz + hz + bhz);
        float nl = tanh_fast(in_ + bin + r_*(hn + bhn));
        hnew = (1.0f - z_)*nl + z_*h_old;
      }
      float hp = __shfl(hnew, (lid & 192) + ((lid+8) & 63));
      // ---- publish before poll ----
      if ((lid & 15) == 0){
        F2U pr; pr.f.x=(f16)hnew; pr.f.y=(f16)hp;
        const int j = (u<<4) + (lid>>4);
        const u64 tg = ((u64)(unsigned)(t+1)<<32) | (u64)pr.u;
        store_u64(&F1[p*256 + j], tg);
        if (!noswap) apub64(&S1[p*256 + j], tg);
        h1seq[(size_t)t*256 + j] = pr.f;   // plain; read post-kernel
      }
      // ---- end-of-step polls: stream tag t+2, ring tag t+1 ----
      if (t+1 < S_LEN){
        const u64* pfA = FST + (size_t)(t+1)*256 + lid;
        const u64* psA = SST + (size_t)(t+1)*256 + lid;
        const u64* pfB = F1 + p*256 + lid;
        const u64* psB = S1 + p*256 + lid;
        u64 ca=0, cb=0; bool ga=false, gb=false;
        if (noswap){
          for(;;){
            if(!ga){ u64 v=load_sc0_u64(pfA);
                     if((unsigned)(v>>32)==(unsigned)(t+2)){ca=v;ga=true;} }
            if(!gb){ u64 v=load_sc0_u64(pfB);
                     if((unsigned)(v>>32)==(unsigned)(t+1)){cb=v;gb=true;} }
            if (ga&&gb) break;
            if (--budget < 0) break;
          }
        } else {
          if (fast_ok){
            for (int k=0; k<FAST_TRIES && !gb; ++k){
              u64 v = load_sc0_u64(pfB);
              if ((unsigned)(v>>32) == (unsigned)(t+1)){ cb=v; gb=true; }
              if (!ga){
                v = load_sc0_u64(pfA);
                if ((unsigned)(v>>32) == (unsigned)(t+2)){ ca=v; ga=true; }
              }
            }
            if (!gb) fast_ok = false;
          }
          while (!(ga && gb)){
            if (!ga){
              u64 v = load_sc0_u64(pfA);
              if ((unsigned)(v>>32) == (unsigned)(t+2)){ ca=v; ga=true; }
              if (!ga){
                v = aload64(psA);
                if ((unsigned)(v>>32) == (unsigned)(t+2)){
                  ca=v; ga=true;
                  if (t < VOTE_STEP){
                    u64 vv = load_sc0_u64(pfA);
                    if ((unsigned)(vv>>32) != (unsigned)(t+2)) my_bad = true;
                  }
                }
              }
            }
            if (!gb){
              u64 v = aload64(psB);
              if ((unsigned)(v>>32) == (unsigned)(t+1)){
                cb=v; gb=true;
                if (t < VOTE_STEP){
                  u64 vv = load_sc0_u64(pfB);
                  if ((unsigned)(vv>>32) != (unsigned)(t+1)) my_bad = true;
                }
              }
            }
            if (--budget < 0) break;
          }
        }
        F2U xa; xa.u = (unsigned)ca; shA[p][(lid&7)*32 + (lid>>3)] = xa.f;
        F2U hb; hb.u = (unsigned)cb; shB[p][(lid&7)*32 + (lid>>3)] = hb.f;
      }
      if (t == VOTE_STEP-1 && my_bad) s_bad = 1;
      BAR_LGKM();
    }
  }
}

// ---------------- row-wise log_softmax over 2048, in place ----------------
__global__ __launch_bounds__(256) void logsoftmax_k(float* __restrict__ lp)
{
  const int t = blockIdx.x, lid = threadIdx.x;
  float* row = lp + (size_t)t*2048;
  float4 a = ((const float4*)row)[lid*2];
  float4 b = ((const float4*)row)[lid*2+1];
  float m = fmaxf(fmaxf(fmaxf(a.x,a.y),fmaxf(a.z,a.w)),
                  fmaxf(fmaxf(b.x,b.y),fmaxf(b.z,b.w)));
  #pragma unroll
  for (int off=1; off<64; off<<=1) m = fmaxf(m, __shfl_xor(m, off));
  __shared__ float redm[4], reds[4];
  const int lane = lid & 63, wvi = lid >> 6;
  if (lane==0) redm[wvi] = m;
  __syncthreads();
  m = fmaxf(fmaxf(redm[0],redm[1]), fmaxf(redm[2],redm[3]));
  float s = __expf(a.x-m)+__expf(a.y-m)+__expf(a.z-m)+__expf(a.w-m)
          + __expf(b.x-m)+__expf(b.y-m)+__expf(b.z-m)+__expf(b.w-m);
  #pragma unroll
  for (int off=1; off<64; off<<=1) s += __shfl_xor(s, off);
  if (lane==0) reds[wvi] = s;
  __syncthreads();
  s = reds[0]+reds[1]+reds[2]+reds[3];
  const float lg = m + __logf(s);
  a.x-=lg; a.y-=lg; a.z-=lg; a.w-=lg;
  b.x-=lg; b.y-=lg; b.z-=lg; b.w-=lg;
  ((float4*)row)[lid*2]   = a;
  ((float4*)row)[lid*2+1] = b;
}

// ---------------- values head: one wave per timestep ----------------
__global__ __launch_bounds__(256) void values_k(
    const f16* __restrict__ h1, const float* __restrict__ vW,
    const float* __restrict__ vb, float* __restrict__ outv, int S)
{
  const int gt = (int)((blockIdx.x*256 + threadIdx.x) >> 6);
  if (gt >= S) return;
  const int lane = threadIdx.x & 63;
  const f16* rowp = h1 + (size_t)gt*512;
  float s = 0.f;
  #pragma unroll
  for (int j=0;j<8;j++){
    const int k = lane + (j<<6);
    s += (float)rowp[k] * vW[k];
  }
  #pragma unroll
  for (int off=32; off; off>>=1) s += __shfl_down(s, off);
  if (lane==0) outv[gt] = s + vb[0];
}

extern "C" void kernel_launch(void* const* d_in, const int* in_sizes, int n_in,
                              void* d_out, int out_size, void* d_ws, size_t ws_size,
                              hipStream_t stream) {
  const float* init = (const float*)d_in[0];
  const float* emb  = (const float*)d_in[1];
  const float* Wih0 = (const float*)d_in[2];
  const float* Whh0 = (const float*)d_in[3];
  const float* bih0 = (const float*)d_in[4];
  const float* bhh0 = (const float*)d_in[5];
  const float* Wih1 = (const float*)d_in[6];
  const float* Whh1 = (const float*)d_in[7];
  const float* bih1 = (const float*)d_in[8];
  const float* bhh1 = (const float*)d_in[9];
  const float* actW = (const float*)d_in[10];
  const float* actb = (const float*)d_in[11];
  const float* valW = (const float*)d_in[12];
  const float* valb = (const float*)d_in[13];
  const int*   acts = (const int*)d_in[14];
  const int*   pars = (const int*)d_in[15];
  float* out = (float*)d_out;
  char*  w   = (char*)d_ws;

  f16* h1seq = (f16*)(w + H1SEQ_OFF);
  f16* actWh = (f16*)(w + ACTW_OFF);
  f16* Wih0h = (f16*)(w + WIH0_OFF);
  // d_out overlays (all dead before the logits GEMM writes d_out):
  f16* xi0 = (f16*)d_out;                                  // [0,48M)
  f16* X   = (f16*)((char*)d_out + 48u*1024*1024);         // [48M,80M)
  u64* FST = (u64*)((char*)d_out + 48u*1024*1024);         // [48M,80M) after GEMM0
  u64* SST = (u64*)((char*)d_out + 80u*1024*1024);         // [80M,112M)

  gather_x<<<S_LEN, 256, 0, stream>>>(emb, acts, pars, X);
  cvt_k<<<1536, 256, 0, stream>>>(Wih0, Wih0h, 1536*1024);
  cvt_k<<<1024, 256, 0, stream>>>(actW, actWh, 2048*512);
  init_ctrl<<<1, 256, 0, stream>>>(w);

  // xi0 = X @ W_ih0^T + b_ih0   [S,1536]
  gemm_f16<f16><<<128*12, 256, 0, stream>>>(X, Wih0h, bih0, xi0, S_LEN, 1536, 1024);

  // X is now dead: clear both stream buffers' tags, then run the scan
  hipMemsetAsync(FST, 0, (size_t)S_LEN*256*8, stream);
  hipMemsetAsync(SST, 0, (size_t)S_LEN*256*8, stream);
  scan_rings<<<192, 256, 0, stream>>>(Whh0, bhh0, Wih1, bih1, Whh1, bhh1,
                                      init, xi0, FST, SST, w);

  // logits = h1seq @ action_W^T + action_b -> d_out, then log_softmax in place
  gemm_f16<float><<<128*16, 256, 0, stream>>>(h1seq, actWh, actb, out, S_LEN, NRULES, 512);
  logsoftmax_k<<<S_LEN, 256, 0, stream>>>(out);
  values_k<<<S_LEN/4, 256, 0, stream>>>(h1seq, valW, valb, out + (size_t)S_LEN*NRULES, S_LEN);
}

// Round 13
// 29860.477 us; speedup vs baseline: 1.7983x; 1.1070x over previous
//
#include <hip/hip_runtime.h>
#include <hip/hip_bf16.h>
#include <hip/hip_fp16.h>

typedef _Float16 f16;
typedef _Float16 f16x2 __attribute__((ext_vector_type(2)));
typedef _Float16 f16x4 __attribute__((ext_vector_type(4)));
typedef _Float16 f16x8 __attribute__((ext_vector_type(8)));
typedef float f32x4 __attribute__((ext_vector_type(4)));
typedef unsigned long long u64;

#define S_LEN 16384
#define NRULES 2048
#define CAP 2000000    // safecell spin cap: protocol failure -> bounded abort
#define FAST_TRIES 64  // bounded fastcell probe before sticky fallback

// ---- ws layout (bytes) ----
#define H1SEQ_OFF 0u                    // 16 MB f16 [S][512]
#define ACTW_OFF  (16u*1024*1024)       // 2 MB f16 action_W
#define WIH0_OFF  (18u*1024*1024)       // 3 MB f16 W_ih0
#define HB0F_OFF  (21u*1024*1024)           // 2*256 u64 fastcells ring0
#define HB0S_OFF  (21u*1024*1024 + 4096)    // 2*256 u64 safecells ring0
#define HB1F_OFF  (21u*1024*1024 + 8192)    // 2*256 u64 fastcells ring1
#define HB1S_OFF  (21u*1024*1024 + 12288)   // 2*256 u64 safecells ring1
// d_out overlay: [0,48M) xi0 f16 [S,1536]; [48M,80M) X f16 [S,1024];
//                [80M,112M) h0seq tagged u64 [S][256] (memset 0 per call)

#if __has_builtin(__builtin_amdgcn_rcpf)
#define RCPF(x) __builtin_amdgcn_rcpf(x)
#else
#define RCPF(x) (1.0f/(x))
#endif

union F2U { f16x2 f; unsigned u; };
union H8  { f16x8 v; f16x2 p[4]; };

// conflict-free perm slots (f16x2 units):
// ring0 (T=4): pair j -> (j>>4)*16 + (j&3)*4 + ((j>>2)&3)
__device__ __forceinline__ int slot4(int j){ return ((j>>4)<<4) + ((j&3)<<2) + ((j>>2)&3); }
// ring1 (T=8): pair j -> (j>>5)*32 + (j&7)*4 + ((j>>3)&3)
__device__ __forceinline__ int slot8(int j){ return ((j>>5)<<5) + ((j&7)<<2) + ((j>>3)&3); }

__device__ __forceinline__ float sigf(float x){ return RCPF(1.0f + __expf(-x)); }
__device__ __forceinline__ float tanh_fast(float x){
  float ax = fabsf(x);
  float e = __expf(-2.0f*ax);
  float t = (1.0f - e) * RCPF(1.0f + e);
  return x >= 0.0f ? t : -t;
}
__device__ __forceinline__ float dot2(f16x2 a, f16x2 b, float c){
#if __has_builtin(__builtin_amdgcn_fdot2)
  return __builtin_amdgcn_fdot2(a, b, c, false);
#else
  return c + (float)a.x*(float)b.x + (float)a.y*(float)b.y;
#endif
}
// proven authoritative primitives (coherence point):
__device__ __forceinline__ u64 aload64(const u64* p){
  return __hip_atomic_load(p, __ATOMIC_RELAXED, __HIP_MEMORY_SCOPE_AGENT);
}
__device__ __forceinline__ void apub64(u64* p, u64 v){
  (void)__hip_atomic_exchange(p, v, __ATOMIC_RELAXED, __HIP_MEMORY_SCOPE_AGENT);
}
// fast-path primitives (same-XCD L2), proven r7:
__device__ __forceinline__ u64 load_sc0_u64(const u64* p){
  u64 v;
  asm volatile("global_load_dwordx2 %0, %1, off sc0\n\ts_waitcnt vmcnt(0)"
               : "=v"(v) : "v"(p) : "memory");
  return v;
}
__device__ __forceinline__ void store_u64(u64* p, u64 v){
  asm volatile("global_store_dwordx2 %0, %1, off"
               :: "v"(p), "v"(v) : "memory");
}
// LDS-only barrier (drains lgkm, NOT vmcnt) — xi prefetch stays in flight.
#define BAR_LGKM() asm volatile("s_waitcnt lgkmcnt(0)\n\ts_barrier" ::: "memory")

// ---------------- gather x = [emb[shifted], emb[parent]] as f16 ----------------
__global__ __launch_bounds__(256) void gather_x(
    const float* __restrict__ emb, const int* __restrict__ act,
    const int* __restrict__ par, f16* __restrict__ X)
{
  const int t = blockIdx.x, lid = threadIdx.x;
  const int ia = (t == 0) ? 0 : (act[t-1] + 1);
  const int ip = par[t] + 1;
  const int half = lid >> 7;
  const int k = (lid & 127) << 2;
  const float* src = emb + (size_t)(half ? ip : ia) * 512 + k;
  float4 v = *(const float4*)src;
  f16x4 o; o.x=(f16)v.x; o.y=(f16)v.y; o.z=(f16)v.z; o.w=(f16)v.w;
  *(f16x4*)&X[(size_t)t*1024 + (half<<9) + k] = o;
}

// ---------------- fp32 -> f16 convert ----------------
__global__ __launch_bounds__(256) void cvt_k(const float* __restrict__ in,
                                             f16* __restrict__ out, int n)
{
  const int i = (blockIdx.x*256 + threadIdx.x) << 2;
  if (i >= n) return;
  float4 v = *(const float4*)&in[i];
  f16x4 o; o.x=(f16)v.x; o.y=(f16)v.y; o.z=(f16)v.z; o.w=(f16)v.w;
  *(f16x4*)&out[i] = o;
}

// ---- per-call init: seed tagged h(-1) cells (fast+safe), invalidate parity0 ----
__global__ __launch_bounds__(256) void init_ctrl(const float* __restrict__ init, char* ws)
{
  const int lid = threadIdx.x;
  u64* f0 = (u64*)(ws + HB0F_OFF);
  u64* s0 = (u64*)(ws + HB0S_OFF);
  u64* f1 = (u64*)(ws + HB1F_OFF);
  u64* s1 = (u64*)(ws + HB1S_OFF);
  F2U a; a.f.x=(f16)init[2*lid];     a.f.y=(f16)init[2*lid+1];
  F2U c; c.f.x=(f16)init[512+2*lid]; c.f.y=(f16)init[512+2*lid+1];
  const u64 inval = (u64)0xF0000000u << 32;   // tag never matched
  const u64 sa = (u64)a.u, sc = (u64)c.u;     // parity 1, tag 0 seeds
  f0[lid] = inval; f0[256+lid] = sa;
  s0[lid] = inval; s0[256+lid] = sa;
  f1[lid] = inval; f1[256+lid] = sc;
  s1[lid] = inval; s1[256+lid] = sc;
}

// ---------------- f16 MFMA GEMM: C[M,N] = A[M,K] @ B[N,K]^T + bias ----------------
template<typename OutT>
__global__ __launch_bounds__(256) void gemm_f16(
    const f16* __restrict__ A, const f16* __restrict__ B,
    const float* __restrict__ bias, OutT* __restrict__ C,
    int M, int N, int K)
{
  __shared__ __align__(16) f16 At[4][128][8];
  __shared__ __align__(16) f16 Bt[4][128][8];
  const int lid = threadIdx.x;
  const int mtiles = M >> 7;
  const int bm = blockIdx.x % mtiles;
  const int bn = blockIdx.x / mtiles;
  const int m0 = bm << 7, n0 = bn << 7;
  const int lane = lid & 63, w = lid >> 6;
  const int wm = (w >> 1) << 6, wn = (w & 1) << 6;
  f32x4 acc[4][4] = {};
  const int nk = K >> 5;
  const int row1 = lid >> 2, j1 = lid & 3;
  for (int kt = 0; kt < nk; ++kt){
    const int kb = kt << 5;
    *(f16x8*)&At[j1][row1][0]    = *(const f16x8*)&A[(size_t)(m0+row1)*K    + kb + j1*8];
    *(f16x8*)&At[j1][row1+64][0] = *(const f16x8*)&A[(size_t)(m0+row1+64)*K + kb + j1*8];
    *(f16x8*)&Bt[j1][row1][0]    = *(const f16x8*)&B[(size_t)(n0+row1)*K    + kb + j1*8];
    *(f16x8*)&Bt[j1][row1+64][0] = *(const f16x8*)&B[(size_t)(n0+row1+64)*K + kb + j1*8];
    __syncthreads();
    const int kc = lane >> 4, rr = lane & 15;
    f16x8 aF[4], bF[4];
    #pragma unroll
    for (int m=0;m<4;m++) aF[m] = *(const f16x8*)&At[kc][wm + m*16 + rr][0];
    #pragma unroll
    for (int n=0;n<4;n++) bF[n] = *(const f16x8*)&Bt[kc][wn + n*16 + rr][0];
    #pragma unroll
    for (int m=0;m<4;m++)
      #pragma unroll
      for (int n=0;n<4;n++)
        acc[m][n] = __builtin_amdgcn_mfma_f32_16x16x32_f16(aF[m], bF[n], acc[m][n], 0,0,0);
    __syncthreads();
  }
  const int rr = lane & 15, rg = lane >> 4;
  #pragma unroll
  for (int n=0;n<4;n++){
    const int gcol = n0 + wn + n*16 + rr;
    const float bv = bias[gcol];
    #pragma unroll
    for (int m=0;m<4;m++){
      #pragma unroll
      for (int r=0;r<4;r++){
        const int grow = m0 + wm + m*16 + rg*4 + r;
        C[(size_t)grow*N + gcol] = (OutT)(acc[m][n][r] + bv);
      }
    }
  }
}

// -------- r7 tagged rings + conflict-free b128 LDS + clean-probe xi prefetch --------
// grid=128. ring0 = blocks {0,8,..,56}, ring1 = {1,9,..,121} (two XCDs if
// dispatch round-robins; per-thread sticky safecell fallback otherwise).
// Step: poll(start, tag from prev step) -> stage perm-LDS -> [xi prefetch
// q+1] -> BAR_LGKM -> compute (b128 reads) -> publish F(+S,+stream) ->
// __syncthreads (drains publishes+prefetch; r7-proven).
__global__ __launch_bounds__(256, 1) void scan_rings(
    const float* __restrict__ Whh0, const float* __restrict__ bhh0,
    const float* __restrict__ Wih1, const float* __restrict__ bih1,
    const float* __restrict__ Whh1, const float* __restrict__ bhh1,
    const float* __restrict__ init, const f16* __restrict__ xi0,
    u64* __restrict__ h0seq, char* ws)
{
  const int lid = threadIdx.x;
  const int bid = blockIdx.x;
  f16x2* h1seq = (f16x2*)(ws + H1SEQ_OFF);
  u64* hb0f = (u64*)(ws + HB0F_OFF);
  u64* hb0s = (u64*)(ws + HB0S_OFF);
  u64* hb1f = (u64*)(ws + HB1F_OFF);
  u64* hb1s = (u64*)(ws + HB1S_OFF);
  __shared__ __align__(16) f16x2 hx[2][256];
  __shared__ __align__(16) f16x2 hh[2][256];

  const int lane7 = bid & 7, grp = bid >> 3;
  bool fast_ok = true;                 // per-thread sticky fast-path health

  if (lane7 == 0 && grp < 8){
    // ================= ring0: layer 0 =================
    const int b = grp;
    const int ksub = lid & 3, row = (b << 6) + (lid >> 2);
    const bool owner = (ksub == 0);
    f16x2 wr[64], wz[64], wn[64];
    #pragma unroll
    for (int i=0;i<64;i++){
      const int k0 = (ksub + (i<<2)) << 1;
      float2 a = *(const float2*)&Whh0[(size_t)row*512         + k0];
      float2 bb= *(const float2*)&Whh0[(size_t)(512+row)*512   + k0];
      float2 c = *(const float2*)&Whh0[(size_t)(1024+row)*512  + k0];
      wr[i].x=(f16)a.x;  wr[i].y=(f16)a.y;
      wz[i].x=(f16)bb.x; wz[i].y=(f16)bb.y;
      wn[i].x=(f16)c.x;  wn[i].y=(f16)c.y;
    }
    float bhr=0.f, bhz=0.f, bhn=0.f, xr=0.f, xz=0.f, xn=0.f;
    if (owner){
      bhr=bhh0[row]; bhz=bhh0[512+row]; bhn=bhh0[1024+row];
      xr=(float)xi0[row]; xz=(float)xi0[512+row]; xn=(float)xi0[1024+row];
    }
    { F2U s; s.f.x=(f16)init[2*lid]; s.f.y=(f16)init[2*lid+1];
      hx[0][slot4(lid)] = s.f; }
    __syncthreads();

    for (int q=0; q<S_LEN; ++q){
      const int par = (q+1)&1;
      {  // poll parity (q+1)&1, expect tag q (published by peers last step)
        const u64* pf = hb0f + par*256 + lid;
        const u64* ps = hb0s + par*256 + lid;
        u64 cell = 0; bool got = false;
        if (fast_ok){
          for (int k=0;k<FAST_TRIES;k++){
            u64 v = load_sc0_u64(pf);
            if ((unsigned)(v>>32) == (unsigned)q){ cell=v; got=true; break; }
          }
          if (!got) fast_ok = false;   // sticky: safecells from now on
        }
        if (!got){
          int it=0;
          for(;;){ u64 v = aload64(ps);
                   if ((unsigned)(v>>32) == (unsigned)q){ cell=v; break; }
                   if (++it > CAP){ cell=v; break; } }
        }
        F2U cu; cu.u = (unsigned)cell; hx[par][slot4(lid)] = cu.f;
      }
      // xi prefetch for q+1: issued AFTER the poll (probes never queue
      // behind the cold fetch); drains at end-of-step __syncthreads.
      float nxr=0.f, nxz=0.f, nxn=0.f;
      if (owner && q+1 < S_LEN){
        const f16* xp = xi0 + (size_t)(q+1)*1536;
        nxr=(float)xp[row]; nxz=(float)xp[512+row]; nxn=(float)xp[1024+row];
      }
      BAR_LGKM();                      // hx[par] staged (LDS-only drain)
      const f16x2* hbase = &hx[par][ksub<<2];
      float ar=0.f, az=0.f, an=0.f;
      #pragma unroll
      for (int i4=0;i4<16;i4++){
        H8 h; h.v = *(const f16x8*)(hbase + (i4<<4));
        #pragma unroll
        for (int m=0;m<4;m++){
          const int i = (i4<<2)+m;
          ar = dot2(wr[i],h.p[m],ar); az = dot2(wz[i],h.p[m],az); an = dot2(wn[i],h.p[m],an);
        }
      }
      ar += __shfl_xor(ar,1); ar += __shfl_xor(ar,2);
      az += __shfl_xor(az,1); az += __shfl_xor(az,2);
      an += __shfl_xor(an,1); an += __shfl_xor(an,2);
      float hnew = 0.f;
      if (owner){
        f16x2 pr2 = hx[par][slot4(row>>1)];
        float h_old = (row&1) ? (float)pr2.y : (float)pr2.x;
        float r  = sigf(xr + ar + bhr);
        float z  = sigf(xz + az + bhz);
        float nl = tanh_fast(xn + r*(an + bhn));
        hnew = (1.0f - z)*nl + z*h_old;
      }
      float hp = __shfl(hnew, (lid & 192) + ((lid+4) & 63));
      if ((lid & 7) == 0){             // pair (row,row+1) -> one tagged cell
        F2U pr; pr.f.x=(f16)hnew; pr.f.y=(f16)hp;
        const int j = (b<<5) + (lid>>3);
        const u64 tagged = ((u64)(unsigned)(q+1)<<32) | (u64)pr.u;
        store_u64(&hb0f[(q&1)*256 + j], tagged);     // same-XCD L2
        apub64(&hb0s[(q&1)*256 + j], tagged);        // authoritative
        apub64(&h0seq[(size_t)q*256 + j], tagged);   // for ring1 (L3)
      }
      if (owner){ xr=nxr; xz=nxz; xn=nxn; }
      __syncthreads();                 // drains publishes; protects hx (r7)
    }
  } else if (lane7 == 1 && grp < 16){
    // ================= ring1: layer 1 (fused W_ih1 + W_hh1) =================
    const int u = grp;
    const int ksub = lid & 7, row = (u << 5) + (lid >> 3);
    const bool owner = (ksub == 0);
    f16x2 ur[32], uz[32], un[32], vr[32], vz[32], vn[32];
    #pragma unroll
    for (int i=0;i<32;i++){
      const int k0 = (ksub + (i<<3)) << 1;
      float2 a = *(const float2*)&Wih1[(size_t)row*512        + k0];
      float2 bb= *(const float2*)&Wih1[(size_t)(512+row)*512  + k0];
      float2 c = *(const float2*)&Wih1[(size_t)(1024+row)*512 + k0];
      float2 d = *(const float2*)&Whh1[(size_t)row*512        + k0];
      float2 e = *(const float2*)&Whh1[(size_t)(512+row)*512  + k0];
      float2 f = *(const float2*)&Whh1[(size_t)(1024+row)*512 + k0];
      ur[i].x=(f16)a.x;  ur[i].y=(f16)a.y;
      uz[i].x=(f16)bb.x; uz[i].y=(f16)bb.y;
      un[i].x=(f16)c.x;  un[i].y=(f16)c.y;
      vr[i].x=(f16)d.x;  vr[i].y=(f16)d.y;
      vz[i].x=(f16)e.x;  vz[i].y=(f16)e.y;
      vn[i].x=(f16)f.x;  vn[i].y=(f16)f.y;
    }
    float bir=0.f,biz=0.f,bin=0.f, bhr=0.f,bhz=0.f,bhn=0.f;
    if (owner){
      bir=bih1[row]; biz=bih1[512+row]; bin=bih1[1024+row];
      bhr=bhh1[row]; bhz=bhh1[512+row]; bhn=bhh1[1024+row];
    }
    { F2U s; s.f.x=(f16)init[512+2*lid]; s.f.y=(f16)init[512+2*lid+1];
      hh[0][slot8(lid)] = s.f; }
    __syncthreads();

    u64 ca_pref = 0;                   // prefetched h0seq cell for step t
    for (int t=0; t<S_LEN; ++t){
      const int par = (t+1)&1;
      {  // dual poll: h0seq[t] (L3, tag t+1) and own ring cell (L2, tag t)
        const u64* pa = h0seq + (size_t)t*256 + lid;
        const u64* pf = hb1f + par*256 + lid;
        const u64* ps = hb1s + par*256 + lid;
        u64 ca=0, cb=0; bool ga=false, gb=false;
        if ((unsigned)(ca_pref>>32) == (unsigned)(t+1)){ ca=ca_pref; ga=true; }
        if (fast_ok){
          for (int k=0; k<FAST_TRIES && !(ga&&gb); ++k){
            if(!ga){ u64 v=aload64(pa);
                     if((unsigned)(v>>32)==(unsigned)(t+1)){ca=v;ga=true;} }
            if(!gb){ u64 v=load_sc0_u64(pf);
                     if((unsigned)(v>>32)==(unsigned)t){cb=v;gb=true;} }
          }
          if (!gb) fast_ok = false;
        }
        if (!(ga&&gb)){
          int it=0;
          while(!(ga&&gb)){
            if(!ga){ u64 v=aload64(pa);
                     if((unsigned)(v>>32)==(unsigned)(t+1)){ca=v;ga=true;} }
            if(!gb){ u64 v=aload64(ps);
                     if((unsigned)(v>>32)==(unsigned)t){cb=v;gb=true;} }
            if (++it > CAP) break;
          }
        }
        F2U xa; xa.u = (unsigned)ca; hx[par][slot8(lid)] = xa.f;
        F2U hc; hc.u = (unsigned)cb; hh[par][slot8(lid)] = hc.f;
      }
      BAR_LGKM();                      // hx/hh staged (LDS-only drain)
      // prefetch next h0seq cell; drains at end-of-step __syncthreads
      if (t+1 < S_LEN) ca_pref = aload64(h0seq + (size_t)(t+1)*256 + lid);
      const f16x2* xbase = &hx[par][ksub<<2];
      const f16x2* hbase = &hh[par][ksub<<2];
      float ir=0.f, iz=0.f, in_=0.f, hr=0.f, hz=0.f, hn=0.f;
      #pragma unroll
      for (int i4=0;i4<8;i4++){
        H8 xv; xv.v = *(const f16x8*)(xbase + (i4<<5));
        H8 hv; hv.v = *(const f16x8*)(hbase + (i4<<5));
        #pragma unroll
        for (int m=0;m<4;m++){
          const int i = (i4<<2)+m;
          ir = dot2(ur[i],xv.p[m],ir); iz = dot2(uz[i],xv.p[m],iz); in_ = dot2(un[i],xv.p[m],in_);
          hr = dot2(vr[i],hv.p[m],hr); hz = dot2(vz[i],hv.p[m],hz); hn  = dot2(vn[i],hv.p[m],hn);
        }
      }
      #pragma unroll
      for (int d=1; d<8; d<<=1){
        ir += __shfl_xor(ir,d); iz += __shfl_xor(iz,d); in_ += __shfl_xor(in_,d);
        hr += __shfl_xor(hr,d); hz += __shfl_xor(hz,d); hn  += __shfl_xor(hn,d);
      }
      float hnew = 0.f;
      if (owner){
        f16x2 pr2 = hh[par][slot8(row>>1)];
        float h_old = (row&1) ? (float)pr2.y : (float)pr2.x;
        float r  = sigf(ir + bir + hr + bhr);
        float z  = sigf(iz + biz + hz + bhz);
        float nl = tanh_fast(in_ + bin + r*(hn + bhn));
        hnew = (1.0f - z)*nl + z*h_old;
      }
      float hp = __shfl(hnew, (lid & 192) + ((lid+8) & 63));
      if ((lid & 15) == 0){            // pair (row,row+1) -> one cell
        F2U pr; pr.f.x=(f16)hnew; pr.f.y=(f16)hp;
        const int j = (u<<4) + (lid>>4);
        const u64 tagged = ((u64)(unsigned)(t+1)<<32) | (u64)pr.u;
        store_u64(&hb1f[(t&1)*256 + j], tagged);
        apub64(&hb1s[(t&1)*256 + j], tagged);
        h1seq[(size_t)t*256 + j] = pr.f;   // plain; visible at kernel end
      }
      __syncthreads();                 // drains publishes; protects hx/hh (r7)
    }
  }
}

// ---------------- row-wise log_softmax over 2048, in place ----------------
__global__ __launch_bounds__(256) void logsoftmax_k(float* __restrict__ lp)
{
  const int t = blockIdx.x, lid = threadIdx.x;
  float* row = lp + (size_t)t*2048;
  float4 a = ((const float4*)row)[lid*2];
  float4 b = ((const float4*)row)[lid*2+1];
  float m = fmaxf(fmaxf(fmaxf(a.x,a.y),fmaxf(a.z,a.w)),
                  fmaxf(fmaxf(b.x,b.y),fmaxf(b.z,b.w)));
  #pragma unroll
  for (int off=1; off<64; off<<=1) m = fmaxf(m, __shfl_xor(m, off));
  __shared__ float redm[4], reds[4];
  const int lane = lid & 63, wvi = lid >> 6;
  if (lane==0) redm[wvi] = m;
  __syncthreads();
  m = fmaxf(fmaxf(redm[0],redm[1]), fmaxf(redm[2],redm[3]));
  float s = __expf(a.x-m)+__expf(a.y-m)+__expf(a.z-m)+__expf(a.w-m)
          + __expf(b.x-m)+__expf(b.y-m)+__expf(b.z-m)+__expf(b.w-m);
  #pragma unroll
  for (int off=1; off<64; off<<=1) s += __shfl_xor(s, off);
  if (lane==0) reds[wvi] = s;
  __syncthreads();
  s = reds[0]+reds[1]+reds[2]+reds[3];
  const float lg = m + __logf(s);
  a.x-=lg; a.y-=lg; a.z-=lg; a.w-=lg;
  b.x-=lg; b.y-=lg; b.z-=lg; b.w-=lg;
  ((float4*)row)[lid*2]   = a;
  ((float4*)row)[lid*2+1] = b;
}

// ---------------- values head: one wave per timestep ----------------
__global__ __launch_bounds__(256) void values_k(
    const f16* __restrict__ h1, const float* __restrict__ vW,
    const float* __restrict__ vb, float* __restrict__ outv, int S)
{
  const int gt = (int)((blockIdx.x*256 + threadIdx.x) >> 6);
  if (gt >= S) return;
  const int lane = threadIdx.x & 63;
  const f16* rowp = h1 + (size_t)gt*512;
  float s = 0.f;
  #pragma unroll
  for (int j=0;j<8;j++){
    const int k = lane + (j<<6);
    s += (float)rowp[k] * vW[k];
  }
  #pragma unroll
  for (int off=32; off; off>>=1) s += __shfl_down(s, off);
  if (lane==0) outv[gt] = s + vb[0];
}

extern "C" void kernel_launch(void* const* d_in, const int* in_sizes, int n_in,
                              void* d_out, int out_size, void* d_ws, size_t ws_size,
                              hipStream_t stream) {
  const float* init = (const float*)d_in[0];
  const float* emb  = (const float*)d_in[1];
  const float* Wih0 = (const float*)d_in[2];
  const float* Whh0 = (const float*)d_in[3];
  const float* bih0 = (const float*)d_in[4];
  const float* bhh0 = (const float*)d_in[5];
  const float* Wih1 = (const float*)d_in[6];
  const float* Whh1 = (const float*)d_in[7];
  const float* bih1 = (const float*)d_in[8];
  const float* bhh1 = (const float*)d_in[9];
  const float* actW = (const float*)d_in[10];
  const float* actb = (const float*)d_in[11];
  const float* valW = (const float*)d_in[12];
  const float* valb = (const float*)d_in[13];
  const int*   acts = (const int*)d_in[14];
  const int*   pars = (const int*)d_in[15];
  float* out = (float*)d_out;
  char*  w   = (char*)d_ws;

  f16* h1seq = (f16*)(w + H1SEQ_OFF);
  f16* actWh = (f16*)(w + ACTW_OFF);
  f16* Wih0h = (f16*)(w + WIH0_OFF);
  // d_out overlays (all dead before the logits GEMM writes d_out):
  f16* xi0   = (f16*)d_out;                                  // [0,48M)
  f16* X     = (f16*)((char*)d_out + 48u*1024*1024);         // [48M,80M)
  u64* h0seq = (u64*)((char*)d_out + 80u*1024*1024);         // [80M,112M)

  // clear h0seq tags (stale tags from prior replay would short-circuit ring1)
  hipMemsetAsync(h0seq, 0, (size_t)S_LEN*256*8, stream);
  gather_x<<<S_LEN, 256, 0, stream>>>(emb, acts, pars, X);
  cvt_k<<<1536, 256, 0, stream>>>(Wih0, Wih0h, 1536*1024);
  cvt_k<<<1024, 256, 0, stream>>>(actW, actWh, 2048*512);
  init_ctrl<<<1, 256, 0, stream>>>(init, w);

  // xi0 = X @ W_ih0^T + b_ih0   [S,1536]
  gemm_f16<f16><<<128*12, 256, 0, stream>>>(X, Wih0h, bih0, xi0, S_LEN, 1536, 1024);

  // fused two-layer scan: tagged rings (r7 skeleton + b128 LDS + clean probes)
  scan_rings<<<128, 256, 0, stream>>>(Whh0, bhh0, Wih1, bih1, Whh1, bhh1,
                                      init, xi0, h0seq, w);

  // logits = h1seq @ action_W^T + action_b -> d_out, then log_softmax in place
  gemm_f16<float><<<128*16, 256, 0, stream>>>(h1seq, actWh, actb, out, S_LEN, NRULES, 512);
  logsoftmax_k<<<S_LEN, 256, 0, stream>>>(out);
  values_k<<<S_LEN/4, 256, 0, stream>>>(h1seq, valW, valb, out + (size_t)S_LEN*NRULES, S_LEN);
}

// Round 15
// 29846.930 us; speedup vs baseline: 1.7991x; 1.0005x over previous
//
#include <hip/hip_runtime.h>
#include <hip/hip_bf16.h>
#include <hip/hip_fp16.h>

typedef _Float16 f16;
typedef _Float16 f16x2 __attribute__((ext_vector_type(2)));
typedef _Float16 f16x4 __attribute__((ext_vector_type(4)));
typedef _Float16 f16x8 __attribute__((ext_vector_type(8)));
typedef float f32x4 __attribute__((ext_vector_type(4)));
typedef unsigned long long u64;

#define S_LEN 16384
#define NRULES 2048
#define CAP 2000000    // safecell spin cap: protocol failure -> bounded abort
#define FAST_TRIES 64  // bounded fastcell probe before sticky fallback

// ---- ws layout (bytes) ----
#define H1SEQ_OFF 0u                    // 16 MB f16 [S][512]
#define ACTW_OFF  (16u*1024*1024)       // 2 MB f16 action_W
#define WIH0_OFF  (18u*1024*1024)       // 3 MB f16 W_ih0
#define HB0F_OFF  (21u*1024*1024)           // 2*256 u64 fastcells ring0
#define HB0S_OFF  (21u*1024*1024 + 4096)    // 2*256 u64 safecells ring0
#define HB1F_OFF  (21u*1024*1024 + 8192)    // 2*256 u64 fastcells ring1
#define HB1S_OFF  (21u*1024*1024 + 12288)   // 2*256 u64 safecells ring1
// d_out overlay: [0,48M) xi0 f16 [S,1536]; [48M,80M) X f16 [S,1024];
//                [80M,112M) h0seq tagged u64 [S][256] (memset 0 per call)

#if __has_builtin(__builtin_amdgcn_rcpf)
#define RCPF(x) __builtin_amdgcn_rcpf(x)
#else
#define RCPF(x) (1.0f/(x))
#endif

union F2U { f16x2 f; unsigned u; };
union H8  { f16x8 v; f16x2 p[4]; };

// conflict-free perm slots (f16x2 units):
// ring0 (T=4): pair j -> (j>>4)*16 + (j&3)*4 + ((j>>2)&3)
__device__ __forceinline__ int slot4(int j){ return ((j>>4)<<4) + ((j&3)<<2) + ((j>>2)&3); }
// ring1 (T=8): pair j -> (j>>5)*32 + (j&7)*4 + ((j>>3)&3)
__device__ __forceinline__ int slot8(int j){ return ((j>>5)<<5) + ((j&7)<<2) + ((j>>3)&3); }

__device__ __forceinline__ float sigf(float x){ return RCPF(1.0f + __expf(-x)); }
__device__ __forceinline__ float tanh_fast(float x){
  float ax = fabsf(x);
  float e = __expf(-2.0f*ax);
  float t = (1.0f - e) * RCPF(1.0f + e);
  return x >= 0.0f ? t : -t;
}
__device__ __forceinline__ float dot2(f16x2 a, f16x2 b, float c){
#if __has_builtin(__builtin_amdgcn_fdot2)
  return __builtin_amdgcn_fdot2(a, b, c, false);
#else
  return c + (float)a.x*(float)b.x + (float)a.y*(float)b.y;
#endif
}
// proven authoritative primitives (coherence point):
__device__ __forceinline__ u64 aload64(const u64* p){
  return __hip_atomic_load(p, __ATOMIC_RELAXED, __HIP_MEMORY_SCOPE_AGENT);
}
__device__ __forceinline__ void apub64(u64* p, u64 v){
  (void)__hip_atomic_exchange(p, v, __ATOMIC_RELAXED, __HIP_MEMORY_SCOPE_AGENT);
}
// fast-path primitives (same-XCD L2), proven r7:
__device__ __forceinline__ u64 load_sc0_u64(const u64* p){
  u64 v;
  asm volatile("global_load_dwordx2 %0, %1, off sc0\n\ts_waitcnt vmcnt(0)"
               : "=v"(v) : "v"(p) : "memory");
  return v;
}
__device__ __forceinline__ void store_u64(u64* p, u64 v){
  asm volatile("global_store_dwordx2 %0, %1, off"
               :: "v"(p), "v"(v) : "memory");
}
// LDS-only barrier (drains lgkm, NOT vmcnt) — xi prefetch stays in flight.
#define BAR_LGKM() asm volatile("s_waitcnt lgkmcnt(0)\n\ts_barrier" ::: "memory")

// ---------------- gather x = [emb[shifted], emb[parent]] as f16 ----------------
__global__ __launch_bounds__(256) void gather_x(
    const float* __restrict__ emb, const int* __restrict__ act,
    const int* __restrict__ par, f16* __restrict__ X)
{
  const int t = blockIdx.x, lid = threadIdx.x;
  const int ia = (t == 0) ? 0 : (act[t-1] + 1);
  const int ip = par[t] + 1;
  const int half = lid >> 7;
  const int k = (lid & 127) << 2;
  const float* src = emb + (size_t)(half ? ip : ia) * 512 + k;
  float4 v = *(const float4*)src;
  f16x4 o; o.x=(f16)v.x; o.y=(f16)v.y; o.z=(f16)v.z; o.w=(f16)v.w;
  *(f16x4*)&X[(size_t)t*1024 + (half<<9) + k] = o;
}

// ---------------- fp32 -> f16 convert ----------------
__global__ __launch_bounds__(256) void cvt_k(const float* __restrict__ in,
                                             f16* __restrict__ out, int n)
{
  const int i = (blockIdx.x*256 + threadIdx.x) << 2;
  if (i >= n) return;
  float4 v = *(const float4*)&in[i];
  f16x4 o; o.x=(f16)v.x; o.y=(f16)v.y; o.z=(f16)v.z; o.w=(f16)v.w;
  *(f16x4*)&out[i] = o;
}

// ---- per-call init: seed tagged h(-1) cells (fast+safe), invalidate parity0 ----
__global__ __launch_bounds__(256) void init_ctrl(const float* __restrict__ init, char* ws)
{
  const int lid = threadIdx.x;
  u64* f0 = (u64*)(ws + HB0F_OFF);
  u64* s0 = (u64*)(ws + HB0S_OFF);
  u64* f1 = (u64*)(ws + HB1F_OFF);
  u64* s1 = (u64*)(ws + HB1S_OFF);
  F2U a; a.f.x=(f16)init[2*lid];     a.f.y=(f16)init[2*lid+1];
  F2U c; c.f.x=(f16)init[512+2*lid]; c.f.y=(f16)init[512+2*lid+1];
  const u64 inval = (u64)0xF0000000u << 32;   // tag never matched
  const u64 sa = (u64)a.u, sc = (u64)c.u;     // parity 1, tag 0 seeds
  f0[lid] = inval; f0[256+lid] = sa;
  s0[lid] = inval; s0[256+lid] = sa;
  f1[lid] = inval; f1[256+lid] = sc;
  s1[lid] = inval; s1[256+lid] = sc;
}

// ---------------- f16 MFMA GEMM: C[M,N] = A[M,K] @ B[N,K]^T + bias ----------------
template<typename OutT>
__global__ __launch_bounds__(256) void gemm_f16(
    const f16* __restrict__ A, const f16* __restrict__ B,
    const float* __restrict__ bias, OutT* __restrict__ C,
    int M, int N, int K)
{
  __shared__ __align__(16) f16 At[4][128][8];
  __shared__ __align__(16) f16 Bt[4][128][8];
  const int lid = threadIdx.x;
  const int mtiles = M >> 7;
  const int bm = blockIdx.x % mtiles;
  const int bn = blockIdx.x / mtiles;
  const int m0 = bm << 7, n0 = bn << 7;
  const int lane = lid & 63, w = lid >> 6;
  const int wm = (w >> 1) << 6, wn = (w & 1) << 6;
  f32x4 acc[4][4] = {};
  const int nk = K >> 5;
  const int row1 = lid >> 2, j1 = lid & 3;
  for (int kt = 0; kt < nk; ++kt){
    const int kb = kt << 5;
    *(f16x8*)&At[j1][row1][0]    = *(const f16x8*)&A[(size_t)(m0+row1)*K    + kb + j1*8];
    *(f16x8*)&At[j1][row1+64][0] = *(const f16x8*)&A[(size_t)(m0+row1+64)*K + kb + j1*8];
    *(f16x8*)&Bt[j1][row1][0]    = *(const f16x8*)&B[(size_t)(n0+row1)*K    + kb + j1*8];
    *(f16x8*)&Bt[j1][row1+64][0] = *(const f16x8*)&B[(size_t)(n0+row1+64)*K + kb + j1*8];
    __syncthreads();
    const int kc = lane >> 4, rr = lane & 15;
    f16x8 aF[4], bF[4];
    #pragma unroll
    for (int m=0;m<4;m++) aF[m] = *(const f16x8*)&At[kc][wm + m*16 + rr][0];
    #pragma unroll
    for (int n=0;n<4;n++) bF[n] = *(const f16x8*)&Bt[kc][wn + n*16 + rr][0];
    #pragma unroll
    for (int m=0;m<4;m++)
      #pragma unroll
      for (int n=0;n<4;n++)
        acc[m][n] = __builtin_amdgcn_mfma_f32_16x16x32_f16(aF[m], bF[n], acc[m][n], 0,0,0);
    __syncthreads();
  }
  const int rr = lane & 15, rg = lane >> 4;
  #pragma unroll
  for (int n=0;n<4;n++){
    const int gcol = n0 + wn + n*16 + rr;
    const float bv = bias[gcol];
    #pragma unroll
    for (int m=0;m<4;m++){
      #pragma unroll
      for (int r=0;r<4;r++){
        const int grow = m0 + wm + m*16 + rg*4 + r;
        C[(size_t)grow*N + gcol] = (OutT)(acc[m][n][r] + bv);
      }
    }
  }
}

// -------- r7 tagged rings + conflict-free b128 LDS + clean-probe xi prefetch --------
// grid=128. ring0 = blocks {0,8,..,56}, ring1 = {1,9,..,121} (two XCDs if
// dispatch round-robins; per-thread sticky safecell fallback otherwise).
// Step: poll(start, tag from prev step) -> stage perm-LDS -> [xi prefetch
// q+1] -> BAR_LGKM -> compute (b128 reads) -> publish F(+S,+stream) ->
// __syncthreads (drains publishes+prefetch; r7-proven).
__global__ __launch_bounds__(256, 1) void scan_rings(
    const float* __restrict__ Whh0, const float* __restrict__ bhh0,
    const float* __restrict__ Wih1, const float* __restrict__ bih1,
    const float* __restrict__ Whh1, const float* __restrict__ bhh1,
    const float* __restrict__ init, const f16* __restrict__ xi0,
    u64* __restrict__ h0seq, char* ws)
{
  const int lid = threadIdx.x;
  const int bid = blockIdx.x;
  f16x2* h1seq = (f16x2*)(ws + H1SEQ_OFF);
  u64* hb0f = (u64*)(ws + HB0F_OFF);
  u64* hb0s = (u64*)(ws + HB0S_OFF);
  u64* hb1f = (u64*)(ws + HB1F_OFF);
  u64* hb1s = (u64*)(ws + HB1S_OFF);
  __shared__ __align__(16) f16x2 hx[2][256];
  __shared__ __align__(16) f16x2 hh[2][256];

  const int lane7 = bid & 7, grp = bid >> 3;
  bool fast_ok = true;                 // per-thread sticky fast-path health

  if (lane7 == 0 && grp < 8){
    // ================= ring0: layer 0 =================
    const int b = grp;
    const int ksub = lid & 3, row = (b << 6) + (lid >> 2);
    const bool owner = (ksub == 0);
    f16x2 wr[64], wz[64], wn[64];
    #pragma unroll
    for (int i=0;i<64;i++){
      const int k0 = (ksub + (i<<2)) << 1;
      float2 a = *(const float2*)&Whh0[(size_t)row*512         + k0];
      float2 bb= *(const float2*)&Whh0[(size_t)(512+row)*512   + k0];
      float2 c = *(const float2*)&Whh0[(size_t)(1024+row)*512  + k0];
      wr[i].x=(f16)a.x;  wr[i].y=(f16)a.y;
      wz[i].x=(f16)bb.x; wz[i].y=(f16)bb.y;
      wn[i].x=(f16)c.x;  wn[i].y=(f16)c.y;
    }
    float bhr=0.f, bhz=0.f, bhn=0.f, xr=0.f, xz=0.f, xn=0.f;
    if (owner){
      bhr=bhh0[row]; bhz=bhh0[512+row]; bhn=bhh0[1024+row];
      xr=(float)xi0[row]; xz=(float)xi0[512+row]; xn=(float)xi0[1024+row];
    }
    { F2U s; s.f.x=(f16)init[2*lid]; s.f.y=(f16)init[2*lid+1];
      hx[0][slot4(lid)] = s.f; }
    __syncthreads();

    for (int q=0; q<S_LEN; ++q){
      const int par = (q+1)&1;
      {  // poll parity (q+1)&1, expect tag q (published by peers last step)
        const u64* pf = hb0f + par*256 + lid;
        const u64* ps = hb0s + par*256 + lid;
        u64 cell = 0; bool got = false;
        if (fast_ok){
          for (int k=0;k<FAST_TRIES;k++){
            u64 v = load_sc0_u64(pf);
            if ((unsigned)(v>>32) == (unsigned)q){ cell=v; got=true; break; }
          }
          if (!got) fast_ok = false;   // sticky: safecells from now on
        }
        if (!got){
          int it=0;
          for(;;){ u64 v = aload64(ps);
                   if ((unsigned)(v>>32) == (unsigned)q){ cell=v; break; }
                   if (++it > CAP){ cell=v; break; } }
        }
        F2U cu; cu.u = (unsigned)cell; hx[par][slot4(lid)] = cu.f;
      }
      // xi prefetch for q+1: issued AFTER the poll (probes never queue
      // behind the cold fetch); drains at end-of-step __syncthreads.
      float nxr=0.f, nxz=0.f, nxn=0.f;
      if (owner && q+1 < S_LEN){
        const f16* xp = xi0 + (size_t)(q+1)*1536;
        nxr=(float)xp[row]; nxz=(float)xp[512+row]; nxn=(float)xp[1024+row];
      }
      BAR_LGKM();                      // hx[par] staged (LDS-only drain)
      const f16x2* hbase = &hx[par][ksub<<2];
      float ar=0.f, az=0.f, an=0.f;
      #pragma unroll
      for (int i4=0;i4<16;i4++){
        H8 h; h.v = *(const f16x8*)(hbase + (i4<<4));
        #pragma unroll
        for (int m=0;m<4;m++){
          const int i = (i4<<2)+m;
          ar = dot2(wr[i],h.p[m],ar); az = dot2(wz[i],h.p[m],az); an = dot2(wn[i],h.p[m],an);
        }
      }
      ar += __shfl_xor(ar,1); ar += __shfl_xor(ar,2);
      az += __shfl_xor(az,1); az += __shfl_xor(az,2);
      an += __shfl_xor(an,1); an += __shfl_xor(an,2);
      float hnew = 0.f;
      if (owner){
        f16x2 pr2 = hx[par][slot4(row>>1)];
        float h_old = (row&1) ? (float)pr2.y : (float)pr2.x;
        float r  = sigf(xr + ar + bhr);
        float z  = sigf(xz + az + bhz);
        float nl = tanh_fast(xn + r*(an + bhn));
        hnew = (1.0f - z)*nl + z*h_old;
      }
      float hp = __shfl(hnew, (lid & 192) + ((lid+4) & 63));
      if ((lid & 7) == 0){             // pair (row,row+1) -> one tagged cell
        F2U pr; pr.f.x=(f16)hnew; pr.f.y=(f16)hp;
        const int j = (b<<5) + (lid>>3);
        const u64 tagged = ((u64)(unsigned)(q+1)<<32) | (u64)pr.u;
        store_u64(&hb0f[(q&1)*256 + j], tagged);     // same-XCD L2
        apub64(&hb0s[(q&1)*256 + j], tagged);        // authoritative
        apub64(&h0seq[(size_t)q*256 + j], tagged);   // for ring1 (L3)
      }
      if (owner){ xr=nxr; xz=nxz; xn=nxn; }
      __syncthreads();                 // drains publishes; protects hx (r7)
    }
  } else if (lane7 == 1 && grp < 16){
    // ================= ring1: layer 1 (fused W_ih1 + W_hh1) =================
    const int u = grp;
    const int ksub = lid & 7, row = (u << 5) + (lid >> 3);
    const bool owner = (ksub == 0);
    f16x2 ur[32], uz[32], un[32], vr[32], vz[32], vn[32];
    #pragma unroll
    for (int i=0;i<32;i++){
      const int k0 = (ksub + (i<<3)) << 1;
      float2 a = *(const float2*)&Wih1[(size_t)row*512        + k0];
      float2 bb= *(const float2*)&Wih1[(size_t)(512+row)*512  + k0];
      float2 c = *(const float2*)&Wih1[(size_t)(1024+row)*512 + k0];
      float2 d = *(const float2*)&Whh1[(size_t)row*512        + k0];
      float2 e = *(const float2*)&Whh1[(size_t)(512+row)*512  + k0];
      float2 f = *(const float2*)&Whh1[(size_t)(1024+row)*512 + k0];
      ur[i].x=(f16)a.x;  ur[i].y=(f16)a.y;
      uz[i].x=(f16)bb.x; uz[i].y=(f16)bb.y;
      un[i].x=(f16)c.x;  un[i].y=(f16)c.y;
      vr[i].x=(f16)d.x;  vr[i].y=(f16)d.y;
      vz[i].x=(f16)e.x;  vz[i].y=(f16)e.y;
      vn[i].x=(f16)f.x;  vn[i].y=(f16)f.y;
    }
    float bir=0.f,biz=0.f,bin=0.f, bhr=0.f,bhz=0.f,bhn=0.f;
    if (owner){
      bir=bih1[row]; biz=bih1[512+row]; bin=bih1[1024+row];
      bhr=bhh1[row]; bhz=bhh1[512+row]; bhn=bhh1[1024+row];
    }
    { F2U s; s.f.x=(f16)init[512+2*lid]; s.f.y=(f16)init[512+2*lid+1];
      hh[0][slot8(lid)] = s.f; }
    __syncthreads();

    u64 ca_pref = 0;                   // prefetched h0seq cell for step t
    for (int t=0; t<S_LEN; ++t){
      const int par = (t+1)&1;
      {  // dual poll: h0seq[t] (L3, tag t+1) and own ring cell (L2, tag t)
        const u64* pa = h0seq + (size_t)t*256 + lid;
        const u64* pf = hb1f + par*256 + lid;
        const u64* ps = hb1s + par*256 + lid;
        u64 ca=0, cb=0; bool ga=false, gb=false;
        if ((unsigned)(ca_pref>>32) == (unsigned)(t+1)){ ca=ca_pref; ga=true; }
        if (fast_ok){
          for (int k=0; k<FAST_TRIES && !(ga&&gb); ++k){
            if(!ga){ u64 v=aload64(pa);
                     if((unsigned)(v>>32)==(unsigned)(t+1)){ca=v;ga=true;} }
            if(!gb){ u64 v=load_sc0_u64(pf);
                     if((unsigned)(v>>32)==(unsigned)t){cb=v;gb=true;} }
          }
          if (!gb) fast_ok = false;
        }
        if (!(ga&&gb)){
          int it=0;
          while(!(ga&&gb)){
            if(!ga){ u64 v=aload64(pa);
                     if((unsigned)(v>>32)==(unsigned)(t+1)){ca=v;ga=true;} }
            if(!gb){ u64 v=aload64(ps);
                     if((unsigned)(v>>32)==(unsigned)t){cb=v;gb=true;} }
            if (++it > CAP) break;
          }
        }
        F2U xa; xa.u = (unsigned)ca; hx[par][slot8(lid)] = xa.f;
        F2U hc; hc.u = (unsigned)cb; hh[par][slot8(lid)] = hc.f;
      }
      BAR_LGKM();                      // hx/hh staged (LDS-only drain)
      // prefetch next h0seq cell; drains at end-of-step __syncthreads
      if (t+1 < S_LEN) ca_pref = aload64(h0seq + (size_t)(t+1)*256 + lid);
      const f16x2* xbase = &hx[par][ksub<<2];
      const f16x2* hbase = &hh[par][ksub<<2];
      float ir=0.f, iz=0.f, in_=0.f, hr=0.f, hz=0.f, hn=0.f;
      #pragma unroll
      for (int i4=0;i4<8;i4++){
        H8 xv; xv.v = *(const f16x8*)(xbase + (i4<<5));
        H8 hv; hv.v = *(const f16x8*)(hbase + (i4<<5));
        #pragma unroll
        for (int m=0;m<4;m++){
          const int i = (i4<<2)+m;
          ir = dot2(ur[i],xv.p[m],ir); iz = dot2(uz[i],xv.p[m],iz); in_ = dot2(un[i],xv.p[m],in_);
          hr = dot2(vr[i],hv.p[m],hr); hz = dot2(vz[i],hv.p[m],hz); hn  = dot2(vn[i],hv.p[m],hn);
        }
      }
      #pragma unroll
      for (int d=1; d<8; d<<=1){
        ir += __shfl_xor(ir,d); iz += __shfl_xor(iz,d); in_ += __shfl_xor(in_,d);
        hr += __shfl_xor(hr,d); hz += __shfl_xor(hz,d); hn  += __shfl_xor(hn,d);
      }
      float hnew = 0.f;
      if (owner){
        f16x2 pr2 = hh[par][slot8(row>>1)];
        float h_old = (row&1) ? (float)pr2.y : (float)pr2.x;
        float r  = sigf(ir + bir + hr + bhr);
        float z  = sigf(iz + biz + hz + bhz);
        float nl = tanh_fast(in_ + bin + r*(hn + bhn));
        hnew = (1.0f - z)*nl + z*h_old;
      }
      float hp = __shfl(hnew, (lid & 192) + ((lid+8) & 63));
      if ((lid & 15) == 0){            // pair (row,row+1) -> one cell
        F2U pr; pr.f.x=(f16)hnew; pr.f.y=(f16)hp;
        const int j = (u<<4) + (lid>>4);
        const u64 tagged = ((u64)(unsigned)(t+1)<<32) | (u64)pr.u;
        store_u64(&hb1f[(t&1)*256 + j], tagged);
        apub64(&hb1s[(t&1)*256 + j], tagged);
        h1seq[(size_t)t*256 + j] = pr.f;   // plain; visible at kernel end
      }
      __syncthreads();                 // drains publishes; protects hx/hh (r7)
    }
  }
}

// ---------------- row-wise log_softmax over 2048, in place ----------------
__global__ __launch_bounds__(256) void logsoftmax_k(float* __restrict__ lp)
{
  const int t = blockIdx.x, lid = threadIdx.x;
  float* row = lp + (size_t)t*2048;
  float4 a = ((const float4*)row)[lid*2];
  float4 b = ((const float4*)row)[lid*2+1];
  float m = fmaxf(fmaxf(fmaxf(a.x,a.y),fmaxf(a.z,a.w)),
                  fmaxf(fmaxf(b.x,b.y),fmaxf(b.z,b.w)));
  #pragma unroll
  for (int off=1; off<64; off<<=1) m = fmaxf(m, __shfl_xor(m, off));
  __shared__ float redm[4], reds[4];
  const int lane = lid & 63, wvi = lid >> 6;
  if (lane==0) redm[wvi] = m;
  __syncthreads();
  m = fmaxf(fmaxf(redm[0],redm[1]), fmaxf(redm[2],redm[3]));
  float s = __expf(a.x-m)+__expf(a.y-m)+__expf(a.z-m)+__expf(a.w-m)
          + __expf(b.x-m)+__expf(b.y-m)+__expf(b.z-m)+__expf(b.w-m);
  #pragma unroll
  for (int off=1; off<64; off<<=1) s += __shfl_xor(s, off);
  if (lane==0) reds[wvi] = s;
  __syncthreads();
  s = reds[0]+reds[1]+reds[2]+reds[3];
  const float lg = m + __logf(s);
  a.x-=lg; a.y-=lg; a.z-=lg; a.w-=lg;
  b.x-=lg; b.y-=lg; b.z-=lg; b.w-=lg;
  ((float4*)row)[lid*2]   = a;
  ((float4*)row)[lid*2+1] = b;
}

// ---------------- values head: one wave per timestep ----------------
__global__ __launch_bounds__(256) void values_k(
    const f16* __restrict__ h1, const float* __restrict__ vW,
    const float* __restrict__ vb, float* __restrict__ outv, int S)
{
  const int gt = (int)((blockIdx.x*256 + threadIdx.x) >> 6);
  if (gt >= S) return;
  const int lane = threadIdx.x & 63;
  const f16* rowp = h1 + (size_t)gt*512;
  float s = 0.f;
  #pragma unroll
  for (int j=0;j<8;j++){
    const int k = lane + (j<<6);
    s += (float)rowp[k] * vW[k];
  }
  #pragma unroll
  for (int off=32; off; off>>=1) s += __shfl_down(s, off);
  if (lane==0) outv[gt] = s + vb[0];
}

extern "C" void kernel_launch(void* const* d_in, const int* in_sizes, int n_in,
                              void* d_out, int out_size, void* d_ws, size_t ws_size,
                              hipStream_t stream) {
  const float* init = (const float*)d_in[0];
  const float* emb  = (const float*)d_in[1];
  const float* Wih0 = (const float*)d_in[2];
  const float* Whh0 = (const float*)d_in[3];
  const float* bih0 = (const float*)d_in[4];
  const float* bhh0 = (const float*)d_in[5];
  const float* Wih1 = (const float*)d_in[6];
  const float* Whh1 = (const float*)d_in[7];
  const float* bih1 = (const float*)d_in[8];
  const float* bhh1 = (const float*)d_in[9];
  const float* actW = (const float*)d_in[10];
  const float* actb = (const float*)d_in[11];
  const float* valW = (const float*)d_in[12];
  const float* valb = (const float*)d_in[13];
  const int*   acts = (const int*)d_in[14];
  const int*   pars = (const int*)d_in[15];
  float* out = (float*)d_out;
  char*  w   = (char*)d_ws;

  f16* h1seq = (f16*)(w + H1SEQ_OFF);
  f16* actWh = (f16*)(w + ACTW_OFF);
  f16* Wih0h = (f16*)(w + WIH0_OFF);
  // d_out overlays (all dead before the logits GEMM writes d_out):
  f16* xi0   = (f16*)d_out;                                  // [0,48M)
  f16* X     = (f16*)((char*)d_out + 48u*1024*1024);         // [48M,80M)
  u64* h0seq = (u64*)((char*)d_out + 80u*1024*1024);         // [80M,112M)

  // clear h0seq tags (stale tags from prior replay would short-circuit ring1)
  hipMemsetAsync(h0seq, 0, (size_t)S_LEN*256*8, stream);
  gather_x<<<S_LEN, 256, 0, stream>>>(emb, acts, pars, X);
  cvt_k<<<1536, 256, 0, stream>>>(Wih0, Wih0h, 1536*1024);
  cvt_k<<<1024, 256, 0, stream>>>(actW, actWh, 2048*512);
  init_ctrl<<<1, 256, 0, stream>>>(init, w);

  // xi0 = X @ W_ih0^T + b_ih0   [S,1536]
  gemm_f16<f16><<<128*12, 256, 0, stream>>>(X, Wih0h, bih0, xi0, S_LEN, 1536, 1024);

  // fused two-layer scan: tagged rings (r7 skeleton + b128 LDS + clean probes)
  scan_rings<<<128, 256, 0, stream>>>(Whh0, bhh0, Wih1, bih1, Whh1, bhh1,
                                      init, xi0, h0seq, w);

  // logits = h1seq @ action_W^T + action_b -> d_out, then log_softmax in place
  gemm_f16<float><<<128*16, 256, 0, stream>>>(h1seq, actWh, actb, out, S_LEN, NRULES, 512);
  logsoftmax_k<<<S_LEN, 256, 0, stream>>>(out);
  values_k<<<S_LEN/4, 256, 0, stream>>>(h1seq, valW, valb, out + (size_t)S_LEN*NRULES, S_LEN);
}